// Round 13
// baseline (895.946 us; speedup 1.0000x reference)
//
#include <hip/hip_runtime.h>
#include <hip/hip_bf16.h>
#include <stdint.h>

#define DEVI __device__ __forceinline__

typedef __attribute__((ext_vector_type(8))) short short8;
typedef __attribute__((ext_vector_type(4))) short short4b;
typedef __attribute__((ext_vector_type(4))) float f32x4;

constexpr int Bb  = 2, Ss = 1024, Dd = 2048, Hh = 16, HKVv = 8, HDd = 128;
constexpr int Ff  = 5632, Ee = 8, Rr = 16;
constexpr int Tt  = Bb * Ss;        // 2048 tokens
constexpr int M2  = 2 * Tt;         // 4096 (token,slot) rows
constexpr int NKV = HKVv * HDd;     // 1024
constexpr int NQKV = Dd + 2 * NKV;  // 4096 fused qkv width
constexpr int F2  = 2 * Ff;         // 11264 fused c1|c3 width

// ---------- small helpers ----------
DEVI unsigned short f2bf(float f) {
  union { float f; unsigned u; } x; x.f = f;
  unsigned r = (x.u + 0x7FFFu + ((x.u >> 16) & 1u)) >> 16;
  return (unsigned short)r;
}
DEVI float bf2f(unsigned short h) {
  union { unsigned u; float f; } x; x.u = ((unsigned)h) << 16; return x.f;
}
DEVI float wsum64(float v) {
  #pragma unroll
  for (int d = 1; d < 64; d <<= 1) v += __shfl_xor(v, d, 64);
  return v;
}
DEVI float wsum16(float v) {
  v += __shfl_xor(v, 1, 64); v += __shfl_xor(v, 2, 64);
  v += __shfl_xor(v, 4, 64); v += __shfl_xor(v, 8, 64);
  return v;
}
DEVI float wmax16(float v) {
  v = fmaxf(v, __shfl_xor(v, 1, 64)); v = fmaxf(v, __shfl_xor(v, 2, 64));
  v = fmaxf(v, __shfl_xor(v, 4, 64)); v = fmaxf(v, __shfl_xor(v, 8, 64));
  return v;
}
typedef __attribute__((address_space(1))) void gvoid;
typedef __attribute__((address_space(3))) void lvoid;
DEVI void gl_lds16(const void* g, void* l) {
  __builtin_amdgcn_global_load_lds((gvoid*)g, (lvoid*)l, 16, 0, 0);
}
DEVI unsigned ldsoff(const void* p) {
  return (unsigned)(uintptr_t)(lvoid*)p;
}
DEVI f32x4 mfma16x16(short8 a, short8 b, f32x4 c) {
  return __builtin_amdgcn_mfma_f32_16x16x32_bf16(a, b, c, 0, 0, 0);
}

// ---------- casts ----------
__global__ __launch_bounds__(256) void cast_w(const float* __restrict__ in,
                                              unsigned short* __restrict__ out, int n) {
  int i = (blockIdx.x * 256 + threadIdx.x) * 8;
  if (i >= n) return;
  const float4* p = (const float4*)(in + i);
  float4 a = p[0], b = p[1];
  float v[8] = {a.x,a.y,a.z,a.w,b.x,b.y,b.z,b.w};
  short8 o;
  #pragma unroll
  for (int j = 0; j < 8; ++j) o[j] = (short)f2bf(v[j]);
  *(short8*)(out + i) = o;
}
__global__ __launch_bounds__(256) void cast_split_w(const float* __restrict__ in,
                                                    unsigned short* __restrict__ oh,
                                                    unsigned short* __restrict__ ol, int n) {
  int i = (blockIdx.x * 256 + threadIdx.x) * 8;
  if (i >= n) return;
  const float4* p = (const float4*)(in + i);
  float4 a = p[0], b = p[1];
  float v[8] = {a.x,a.y,a.z,a.w,b.x,b.y,b.z,b.w};
  short8 h, l;
  #pragma unroll
  for (int j = 0; j < 8; ++j) {
    unsigned short hb = f2bf(v[j]);
    h[j] = (short)hb;
    l[j] = (short)f2bf(v[j] - bf2f(hb));
  }
  *(short8*)(oh + i) = h;
  *(short8*)(ol + i) = l;
}
__global__ __launch_bounds__(256) void zero_f32(float* __restrict__ p, int n) {
  int i = blockIdx.x * 256 + threadIdx.x;
  if (i < n) p[i] = 0.f;
}

// ---------- rmsnorm f32 -> single bf16 ----------
__global__ __launch_bounds__(256) void rmsnorm_k(const float* __restrict__ x,
                                                 const float* __restrict__ w,
                                                 unsigned short* __restrict__ out) {
  int row = blockIdx.x, tid = threadIdx.x;
  const float* xr = x + (size_t)row * Dd;
  const float4* p4 = (const float4*)(xr + tid * 8);
  float4 a = p4[0], b = p4[1];
  float v[8] = {a.x,a.y,a.z,a.w,b.x,b.y,b.z,b.w};
  float ss = 0.f;
  #pragma unroll
  for (int j = 0; j < 8; ++j) ss += v[j] * v[j];
  ss = wsum64(ss);
  __shared__ float red[4];
  int wv_ = tid >> 6, l = tid & 63;
  if (l == 0) red[wv_] = ss;
  __syncthreads();
  float tot = red[0] + red[1] + red[2] + red[3];
  float rstd = rsqrtf(tot * (1.0f / Dd) + 1e-5f);
  const float* wr = w + tid * 8;
  short8 o;
  #pragma unroll
  for (int j = 0; j < 8; ++j) o[j] = (short)f2bf(v[j] * rstd * wr[j]);
  *(short8*)(out + (size_t)row * Dd + tid * 8) = o;
}

// ---------- rmsnorm f32 -> split bf16 pair ----------
__global__ __launch_bounds__(256) void rmsnorm_split_k(const float* __restrict__ x,
                                                       const float* __restrict__ w,
                                                       unsigned short* __restrict__ outh,
                                                       unsigned short* __restrict__ outl) {
  int row = blockIdx.x, tid = threadIdx.x;
  const float* xr = x + (size_t)row * Dd;
  const float4* p4 = (const float4*)(xr + tid * 8);
  float4 a = p4[0], b = p4[1];
  float v[8] = {a.x,a.y,a.z,a.w,b.x,b.y,b.z,b.w};
  float ss = 0.f;
  #pragma unroll
  for (int j = 0; j < 8; ++j) ss += v[j] * v[j];
  ss = wsum64(ss);
  __shared__ float red[4];
  int wv_ = tid >> 6, l = tid & 63;
  if (l == 0) red[wv_] = ss;
  __syncthreads();
  float tot = red[0] + red[1] + red[2] + red[3];
  float rstd = rsqrtf(tot * (1.0f / Dd) + 1e-5f);
  const float* wr = w + tid * 8;
  short8 oh, ol;
  #pragma unroll
  for (int j = 0; j < 8; ++j) {
    float val = v[j] * rstd * wr[j];
    unsigned short hb = f2bf(val);
    oh[j] = (short)hb;
    ol[j] = (short)f2bf(val - bf2f(hb));
  }
  *(short8*)(outh + (size_t)row * Dd + tid * 8) = oh;
  *(short8*)(outl + (size_t)row * Dd + tid * 8) = ol;
}

// ---------- bf16 GEMM v3: 8-wave/512-thread, BK=64, XOR LDS, low-register (acc 2x4) ----------
// COLMAJ=1: by varies fastest (B-panel-stationary; for B-heavy shapes). ks only when COLMAJ=0.
template <int MODE, int COLMAJ>
__global__ __launch_bounds__(512) void gemm_bt64_v3(const unsigned short* __restrict__ A,
                                                    const unsigned short* __restrict__ Bw,
                                                    void* __restrict__ C0,
                                                    void* __restrict__ C1,
                                                    int M, int N, int Kext, int ld, int gx) {
  __shared__ __align__(16) unsigned short As[128 * 64];
  __shared__ __align__(16) unsigned short Bs[128 * 64];
  int tid = threadIdx.x;
  int w = tid >> 6, l = tid & 63;
  int lr = l & 15, lg = l >> 4;
  int cpx = (int)gridDim.x >> 3;
  int bid = blockIdx.x;
  int swz = (bid & 7) * cpx + (bid >> 3);
  int mtiles = M >> 7;
  int bx, by, ks = 0;
  if (COLMAJ) { by = swz % mtiles; bx = swz / mtiles; }
  else {
    bx = swz % gx; by = swz / gx;
    if (by >= mtiles) { ks = 1; by -= mtiles; }
  }
  int m0 = by * 128, n0 = bx * 128;
  int koff = ks * Kext;
  int wr = (w >> 1) * 32, wc = (w & 1) * 64;
  f32x4 acc[2][4];
  #pragma unroll
  for (int i = 0; i < 2; ++i)
    #pragma unroll
    for (int j = 0; j < 4; ++j) acc[i][j] = (f32x4){0.f, 0.f, 0.f, 0.f};

  int srow = w * 16 + (l >> 3);
  int schunk = (l & 7) ^ (l >> 3);
  const unsigned short* ga = A  + (size_t)(m0 + srow) * ld + koff + schunk * 8;
  const unsigned short* gb = Bw + (size_t)(n0 + srow) * ld + koff + schunk * 8;
  unsigned short* lA = As + w * 1024;
  unsigned short* lB = Bs + w * 1024;

  for (int k0 = 0; k0 < Kext; k0 += 64) {
    #pragma unroll
    for (int c = 0; c < 2; ++c) {
      gl_lds16(ga + k0 + (size_t)(c * 8) * ld, lA + c * 512);
      gl_lds16(gb + k0 + (size_t)(c * 8) * ld, lB + c * 512);
    }
    __syncthreads();
    #pragma unroll
    for (int kk = 0; kk < 2; ++kk) {
      int rc = ((kk * 4 + lg) ^ (lr & 7)) * 8;
      short8 af[2], bfr[4];
      #pragma unroll
      for (int i = 0; i < 2; ++i)
        af[i]  = *(const short8*)(As + (wr + i * 16 + lr) * 64 + rc);
      #pragma unroll
      for (int j = 0; j < 4; ++j)
        bfr[j] = *(const short8*)(Bs + (wc + j * 16 + lr) * 64 + rc);
      #pragma unroll
      for (int i = 0; i < 2; ++i)
        #pragma unroll
        for (int j = 0; j < 4; ++j) acc[i][j] = mfma16x16(af[i], bfr[j], acc[i][j]);
    }
    __syncthreads();
  }
  float* Cf = (float*)(ks ? C1 : C0);
  #pragma unroll
  for (int i = 0; i < 2; ++i)
    #pragma unroll
    for (int j = 0; j < 4; ++j) {
      int m = m0 + wr + i * 16 + lg * 4;
      int n = n0 + wc + j * 16 + lr;
      #pragma unroll
      for (int r = 0; r < 4; ++r) {
        float vv = acc[i][j][r];
        size_t o = (size_t)(m + r) * N + n;
        if (MODE == 0) ((unsigned short*)C0)[o] = f2bf(vv);
        else           Cf[o] = vv;
      }
    }
}

// ---------- 3-pass split-bf16 GEMM v3: 8-wave/512-thread, BK=32, swizzle v2 ----------
template <int MODE, int COLMAJ>
__global__ __launch_bounds__(512) void gemm3_v3(const unsigned short* __restrict__ Ah,
                                                const unsigned short* __restrict__ Al,
                                                const unsigned short* __restrict__ Bh1,
                                                const unsigned short* __restrict__ Bl1,
                                                const unsigned short* __restrict__ Bh2,
                                                const unsigned short* __restrict__ Bl2,
                                                const unsigned short* __restrict__ Bh3,
                                                const unsigned short* __restrict__ Bl3,
                                                int nsplit1, int nsplit2,
                                                void* __restrict__ C0,
                                                const float* __restrict__ resid,
                                                int M, int N, int K, int gx) {
  __shared__ __align__(16) unsigned short Ash[128 * 32];
  __shared__ __align__(16) unsigned short Asl[128 * 32];
  __shared__ __align__(16) unsigned short Bsh[128 * 32];
  __shared__ __align__(16) unsigned short Bsl[128 * 32];
  int tid = threadIdx.x;
  int w = tid >> 6, l = tid & 63;
  int lr = l & 15, lg = l >> 4;
  int cpx = (int)gridDim.x >> 3;
  int bid = blockIdx.x;
  int swz = (bid & 7) * cpx + (bid >> 3);
  int mtiles = M >> 7;
  int bx, by;
  if (COLMAJ) { by = swz % mtiles; bx = swz / mtiles; }
  else        { bx = swz % gx;     by = swz / gx; }
  int m0 = by * 128, n0 = bx * 128;
  int wr = (w >> 1) * 32, wc = (w & 1) * 64;

  const unsigned short* Bh; const unsigned short* Bl; int nb;
  if (n0 < nsplit1)      { Bh = Bh1; Bl = Bl1; nb = n0; }
  else if (n0 < nsplit2) { Bh = Bh2; Bl = Bl2; nb = n0 - nsplit1; }
  else                   { Bh = Bh3; Bl = Bl3; nb = n0 - nsplit2; }

  f32x4 acc[2][4];
  #pragma unroll
  for (int i = 0; i < 2; ++i)
    #pragma unroll
    for (int j = 0; j < 4; ++j) acc[i][j] = (f32x4){0.f, 0.f, 0.f, 0.f};

  int srow = w * 16 + (l >> 2);
  int scol = ((l & 3) ^ ((l >> 3) & 3)) * 8;
  const unsigned short* gah = Ah + (size_t)(m0 + srow) * K + scol;
  const unsigned short* gal = Al + (size_t)(m0 + srow) * K + scol;
  const unsigned short* gbh = Bh + (size_t)(nb + srow) * K + scol;
  const unsigned short* gbl = Bl + (size_t)(nb + srow) * K + scol;
  unsigned short* lAh = Ash + w * 512;
  unsigned short* lAl = Asl + w * 512;
  unsigned short* lBh = Bsh + w * 512;
  unsigned short* lBl = Bsl + w * 512;

  for (int k0 = 0; k0 < K; k0 += 32) {
    gl_lds16(gah + k0, lAh);
    gl_lds16(gal + k0, lAl);
    gl_lds16(gbh + k0, lBh);
    gl_lds16(gbl + k0, lBl);
    __syncthreads();
    int rc = (lg ^ ((lr >> 1) & 3)) * 8;
    short8 afh[2], afl[2], bfh[4], bfl[4];
    #pragma unroll
    for (int i = 0; i < 2; ++i) {
      afh[i] = *(const short8*)(Ash + (wr + i * 16 + lr) * 32 + rc);
      afl[i] = *(const short8*)(Asl + (wr + i * 16 + lr) * 32 + rc);
    }
    #pragma unroll
    for (int j = 0; j < 4; ++j) {
      bfh[j] = *(const short8*)(Bsh + (wc + j * 16 + lr) * 32 + rc);
      bfl[j] = *(const short8*)(Bsl + (wc + j * 16 + lr) * 32 + rc);
    }
    #pragma unroll
    for (int i = 0; i < 2; ++i)
      #pragma unroll
      for (int j = 0; j < 4; ++j) {
        acc[i][j] = mfma16x16(afh[i], bfh[j], acc[i][j]);
        acc[i][j] = mfma16x16(afh[i], bfl[j], acc[i][j]);
        acc[i][j] = mfma16x16(afl[i], bfh[j], acc[i][j]);
      }
    __syncthreads();
  }
  #pragma unroll
  for (int i = 0; i < 2; ++i)
    #pragma unroll
    for (int j = 0; j < 4; ++j) {
      int m = m0 + wr + i * 16 + lg * 4;
      int n = n0 + wc + j * 16 + lr;
      #pragma unroll
      for (int r = 0; r < 4; ++r) {
        float vv = acc[i][j][r];
        size_t o = (size_t)(m + r) * N + n;
        if (MODE == 1) ((float*)C0)[o] = vv;
        else           ((float*)C0)[o] = vv + resid[o];
      }
    }
}

// ---------- split-cast V columns of fused qkv f32 buffer ----------
__global__ __launch_bounds__(128) void vsplit_k(const float* __restrict__ qkv,
                                                unsigned short* __restrict__ vh,
                                                unsigned short* __restrict__ vl) {
  int row = blockIdx.x;
  int bas = threadIdx.x * 8;
  const float4* p = (const float4*)(qkv + (size_t)row * NQKV + Dd + NKV + bas);
  float4 a = p[0], b = p[1];
  float v[8] = {a.x,a.y,a.z,a.w,b.x,b.y,b.z,b.w};
  short8 h, l;
  #pragma unroll
  for (int j = 0; j < 8; ++j) {
    unsigned short hb = f2bf(v[j]);
    h[j] = (short)hb;
    l[j] = (short)f2bf(v[j] - bf2f(hb));
  }
  size_t o = (size_t)row * NKV + bas;
  *(short8*)(vh + o) = h;
  *(short8*)(vl + o) = l;
}

// ---------- RoPE on strided f32 rows -> split bf16 pair ----------
__global__ void rope_split_k(const float* __restrict__ x, int xstride,
                             const float* __restrict__ cs, const float* __restrict__ sn,
                             unsigned short* __restrict__ oh, unsigned short* __restrict__ ol,
                             int nh) {
  int row = blockIdx.x;
  int s = row & (Ss - 1);
  int nelem = nh * HDd;
  int bas = threadIdx.x * 8;
  if (bas >= nelem) return;
  const float4* px = (const float4*)(x + (size_t)row * xstride + bas);
  float4 a = px[0], b = px[1];
  float vv[8] = {a.x,a.y,a.z,a.w,b.x,b.y,b.z,b.w};
  int d = bas & (HDd - 1);
  const float* cr = cs + s * 64 + (d >> 1);
  const float* sr = sn + s * 64 + (d >> 1);
  short8 hs, ls;
  #pragma unroll
  for (int p = 0; p < 4; ++p) {
    float x1 = vv[2 * p], x2 = vv[2 * p + 1];
    float c = cr[p], si = sr[p];
    float o1 = x1 * c - x2 * si;
    float o2 = x1 * si + x2 * c;
    unsigned short h1 = f2bf(o1), h2 = f2bf(o2);
    hs[2 * p] = (short)h1;      hs[2 * p + 1] = (short)h2;
    ls[2 * p] = (short)f2bf(o1 - bf2f(h1));
    ls[2 * p + 1] = (short)f2bf(o2 - bf2f(h2));
  }
  size_t o = (size_t)row * nelem + bas;
  *(short8*)(oh + o) = hs;
  *(short8*)(ol + o) = ls;
}

// ---------- flash attention, 3-pass split precision ----------
__global__ __launch_bounds__(256) void attn3_k(const unsigned short* __restrict__ qh,
                                               const unsigned short* __restrict__ ql,
                                               const unsigned short* __restrict__ kh,
                                               const unsigned short* __restrict__ kl,
                                               const unsigned short* __restrict__ vh,
                                               const unsigned short* __restrict__ vl,
                                               const float* __restrict__ mask,
                                               unsigned short* __restrict__ aoh,
                                               unsigned short* __restrict__ aol) {
  __shared__ __align__(16) unsigned short Ksh[32 * 128], Ksl[32 * 128];
  __shared__ __align__(16) unsigned short VTh[8 * 528], VTl[8 * 528];
  __shared__ __align__(16) unsigned short Plh[4 * 16 * 40], Pll[4 * 16 * 40];
  int tid = threadIdx.x, w = tid >> 6, l = tid & 63;
  int lr = l & 15, lg = l >> 4;
  int b = blockIdx.y >> 4, h = blockIdx.y & 15, hk = h >> 1;
  int q0 = blockIdx.x * 64 + w * 16;

  short8 qfh[4], qfl[4];
  {
    size_t qoff = ((size_t)((b * Ss + q0 + lr) * Hh + h)) * HDd;
    #pragma unroll
    for (int ds = 0; ds < 4; ++ds) {
      qfh[ds] = *(const short8*)(qh + qoff + ds * 32 + lg * 8);
      qfl[ds] = *(const short8*)(ql + qoff + ds * 32 + lg * 8);
    }
  }

  float mreg[4] = {-1e30f, -1e30f, -1e30f, -1e30f};
  float lreg[4] = {0.f, 0.f, 0.f, 0.f};
  f32x4 oacc[8];
  #pragma unroll
  for (int db = 0; db < 8; ++db) oacc[db] = (f32x4){0.f, 0.f, 0.f, 0.f};

  const float sc = 0.08838834764831845f;  // 1/sqrt(128)
  size_t kvbase = ((size_t)(b * Ss) * HKVv + hk) * HDd;
  const unsigned short* kb_h = kh + kvbase;
  const unsigned short* kb_l = kl + kvbase;
  const unsigned short* vb_h = vh + kvbase;
  const unsigned short* vb_l = vl + kvbase;

  int kc1 = (lr ^ lg) * 8;
  int kc2 = (lr ^ (lg + 4)) * 8;
  int vrow_a = w * 8 + ((l & 7) >> 1);
  int vchunk = ((l >> 3) * 2 + (l & 1)) * 8;
  unsigned short* vh1 = VTh + (2 * w) * 528;
  unsigned short* vh2 = VTh + (2 * w + 1) * 528;
  unsigned short* vl1 = VTl + (2 * w) * 528;
  unsigned short* vl2 = VTl + (2 * w + 1) * 528;
  unsigned vtbh = ldsoff(VTh) + (unsigned)lr * 8u;
  unsigned vtbl = ldsoff(VTl) + (unsigned)lr * 8u;

  for (int kv0 = 0; kv0 < Ss; kv0 += 32) {
    int r1 = kv0 + w * 8 + lg;
    gl_lds16(kb_h + (size_t)r1 * NKV + kc1,       Ksh + w * 1024);
    gl_lds16(kb_h + (size_t)(r1 + 4) * NKV + kc2, Ksh + w * 1024 + 512);
    gl_lds16(kb_l + (size_t)r1 * NKV + kc1,       Ksl + w * 1024);
    gl_lds16(kb_l + (size_t)(r1 + 4) * NKV + kc2, Ksl + w * 1024 + 512);
    int vr0 = kv0 + vrow_a;
    gl_lds16(vb_h + (size_t)vr0 * NKV + vchunk,       vh1);
    gl_lds16(vb_h + (size_t)(vr0 + 4) * NKV + vchunk, vh2);
    gl_lds16(vb_l + (size_t)vr0 * NKV + vchunk,       vl1);
    gl_lds16(vb_l + (size_t)(vr0 + 4) * NKV + vchunk, vl2);
    __syncthreads();

    f32x4 s0 = (f32x4){0.f,0.f,0.f,0.f}, s1 = (f32x4){0.f,0.f,0.f,0.f};
    #pragma unroll
    for (int ds = 0; ds < 4; ++ds) {
      int kcol = ((ds * 4 + lg) ^ (lr & 7)) * 8;
      short8 kh0 = *(const short8*)(Ksh + lr * 128 + kcol);
      short8 kh1 = *(const short8*)(Ksh + (16 + lr) * 128 + kcol);
      short8 kl0 = *(const short8*)(Ksl + lr * 128 + kcol);
      short8 kl1 = *(const short8*)(Ksl + (16 + lr) * 128 + kcol);
      s0 = mfma16x16(qfh[ds], kh0, s0);
      s0 = mfma16x16(qfh[ds], kl0, s0);
      s0 = mfma16x16(qfl[ds], kh0, s0);
      s1 = mfma16x16(qfh[ds], kh1, s1);
      s1 = mfma16x16(qfh[ds], kl1, s1);
      s1 = mfma16x16(qfl[ds], kh1, s1);
    }
    const float* mrow = mask + (size_t)(q0 + lg * 4) * Ss + kv0 + lr;
    #pragma unroll
    for (int r = 0; r < 4; ++r) {
      float a0 = s0[r] * sc + mrow[(size_t)r * Ss];
      float a1 = s1[r] * sc + mrow[(size_t)r * Ss + 16];
      float t = wmax16(fmaxf(a0, a1));
      float mn = fmaxf(mreg[r], t);
      float resc = __expf(mreg[r] - mn);
      mreg[r] = mn;
      float e0 = __expf(a0 - mn), e1 = __expf(a1 - mn);
      float ps = wsum16(e0 + e1);
      lreg[r] = lreg[r] * resc + ps;
      #pragma unroll
      for (int db = 0; db < 8; ++db) oacc[db][r] *= resc;
      unsigned short h0 = f2bf(e0), h1 = f2bf(e1);
      unsigned short* prowh = Plh + (w * 16 + lg * 4 + r) * 40;
      unsigned short* prowl = Pll + (w * 16 + lg * 4 + r) * 40;
      prowh[lr] = h0;            prowh[16 + lr] = h1;
      prowl[lr] = f2bf(e0 - bf2f(h0));
      prowl[16 + lr] = f2bf(e1 - bf2f(h1));
    }
    asm volatile("" ::: "memory");
    short8 pfh = *(const short8*)(Plh + (w * 16 + lr) * 40 + lg * 8);
    short8 pfl = *(const short8*)(Pll + (w * 16 + lr) * 40 + lg * 8);

    short4b v4[16];
    #pragma unroll
    for (int db = 0; db < 8; ++db) {
      #pragma unroll
      for (int t = 0; t < 2; ++t) {
        unsigned off = vtbh + (unsigned)((lg * 2 + t) * 1056 + db * 128);
        asm volatile("ds_read_b64_tr_b16 %0, %1" : "=v"(v4[db * 2 + t]) : "v"(off));
      }
    }
    asm volatile("s_waitcnt lgkmcnt(0)" ::: "memory");
    __builtin_amdgcn_sched_barrier(0);
    #pragma unroll
    for (int db = 0; db < 8; ++db) {
      short8 vf;
      vf[0] = v4[db*2][0]; vf[1] = v4[db*2][1]; vf[2] = v4[db*2][2]; vf[3] = v4[db*2][3];
      vf[4] = v4[db*2+1][0]; vf[5] = v4[db*2+1][1]; vf[6] = v4[db*2+1][2]; vf[7] = v4[db*2+1][3];
      oacc[db] = mfma16x16(pfh, vf, oacc[db]);
      oacc[db] = mfma16x16(pfl, vf, oacc[db]);
    }
    #pragma unroll
    for (int db = 0; db < 8; ++db) {
      #pragma unroll
      for (int t = 0; t < 2; ++t) {
        unsigned off = vtbl + (unsigned)((lg * 2 + t) * 1056 + db * 128);
        asm volatile("ds_read_b64_tr_b16 %0, %1" : "=v"(v4[db * 2 + t]) : "v"(off));
      }
    }
    asm volatile("s_waitcnt lgkmcnt(0)" ::: "memory");
    __builtin_amdgcn_sched_barrier(0);
    #pragma unroll
    for (int db = 0; db < 8; ++db) {
      short8 vf;
      vf[0] = v4[db*2][0]; vf[1] = v4[db*2][1]; vf[2] = v4[db*2][2]; vf[3] = v4[db*2][3];
      vf[4] = v4[db*2+1][0]; vf[5] = v4[db*2+1][1]; vf[6] = v4[db*2+1][2]; vf[7] = v4[db*2+1][3];
      oacc[db] = mfma16x16(pfh, vf, oacc[db]);
    }
    __syncthreads();
  }
  float inv[4];
  #pragma unroll
  for (int r = 0; r < 4; ++r) inv[r] = 1.0f / lreg[r];
  size_t obase = ((size_t)((b * Ss + q0 + lg * 4) * Hh + h)) * HDd + lr;
  #pragma unroll
  for (int db = 0; db < 8; ++db)
    #pragma unroll
    for (int r = 0; r < 4; ++r) {
      float val = oacc[db][r] * inv[r];
      unsigned short hb = f2bf(val);
      size_t o = obase + (size_t)r * Hh * HDd + db * 16;
      aoh[o] = hb;
      aol[o] = f2bf(val - bf2f(hb));
    }
}

// ---------- router ----------
__global__ __launch_bounds__(256) void router_logits(const float* __restrict__ x2,
                                                     const float* __restrict__ fnw,
                                                     const float* __restrict__ gw,
                                                     float* __restrict__ logits) {
  int wid = (blockIdx.x * 256 + threadIdx.x) >> 6;
  int l = threadIdx.x & 63;
  if (wid >= Tt) return;
  const float* row = x2 + (size_t)wid * Dd;
  float xs[32]; float ss = 0.f;
  #pragma unroll
  for (int c = 0; c < 32; ++c) { float t = row[c * 64 + l]; xs[c] = t; ss += t * t; }
  ss = wsum64(ss);
  float rstd = rsqrtf(ss * (1.0f / Dd) + 1e-5f);
  #pragma unroll
  for (int c = 0; c < 32; ++c) xs[c] *= rstd * fnw[c * 64 + l];
  for (int e = 0; e < 8; ++e) {
    float a = 0.f;
    #pragma unroll
    for (int c = 0; c < 32; ++c) a += xs[c] * gw[(size_t)e * Dd + c * 64 + l];
    a = wsum64(a);
    if (l == 0) logits[wid * 8 + e] = a;
  }
}
__global__ __launch_bounds__(256) void router_colstats(const float* __restrict__ logits,
                                                       float* __restrict__ mz) {
  int b = blockIdx.x >> 3, e = blockIdx.x & 7;
  int tid = threadIdx.x, wv_ = tid >> 6, l = tid & 63;
  __shared__ float red[4];
  float mx = -1e30f;
  for (int s = tid; s < Ss; s += 256) mx = fmaxf(mx, logits[(size_t)(b * Ss + s) * 8 + e]);
  #pragma unroll
  for (int d = 1; d < 64; d <<= 1) mx = fmaxf(mx, __shfl_xor(mx, d, 64));
  if (l == 0) red[wv_] = mx;
  __syncthreads();
  mx = fmaxf(fmaxf(red[0], red[1]), fmaxf(red[2], red[3]));
  __syncthreads();
  float z = 0.f;
  for (int s = tid; s < Ss; s += 256) z += expf(logits[(size_t)(b * Ss + s) * 8 + e] - mx);
  z = wsum64(z);
  if (l == 0) red[wv_] = z;
  __syncthreads();
  if (tid == 0) {
    mz[(b * 8 + e) * 2] = mx;
    mz[(b * 8 + e) * 2 + 1] = red[0] + red[1] + red[2] + red[3];
  }
}
__global__ __launch_bounds__(256) void router_select(const float* __restrict__ logits,
                                                     const float* __restrict__ mz,
                                                     int* __restrict__ sel,
                                                     float* __restrict__ ewt) {
  int t = blockIdx.x * 256 + threadIdx.x;
  if (t >= Tt) return;
  int b = t >> 10;
  float rw[8];
  #pragma unroll
  for (int e = 0; e < 8; ++e)
    rw[e] = expf(logits[(size_t)t * 8 + e] - mz[(b * 8 + e) * 2]) / mz[(b * 8 + e) * 2 + 1];
  int i0 = 0; float b0 = rw[0];
  #pragma unroll
  for (int e = 1; e < 8; ++e) if (rw[e] > b0) { b0 = rw[e]; i0 = e; }
  int i1 = -1; float b1 = -1.f;
  #pragma unroll
  for (int e = 0; e < 8; ++e) if (e != i0 && rw[e] > b1) { b1 = rw[e]; i1 = e; }
  float s = b0 + b1;
  sel[2 * t] = i0; sel[2 * t + 1] = i1;
  ewt[2 * t] = b0 / s; ewt[2 * t + 1] = b1 / s;
}
__global__ void zero_cnt_k(int* cnt) { if (threadIdx.x < 8) cnt[threadIdx.x] = 0; }
__global__ void gather_k(const int* __restrict__ sel, int* cnt, int* list) {
  int i = blockIdx.x * 256 + threadIdx.x;
  if (i >= M2) return;
  int e = sel[i];
  int pos = atomicAdd(cnt + e, 1);
  list[e * Tt + pos] = i;
}

// ---------- LoRA up via MFMA ----------
__global__ __launch_bounds__(64) void lora_up_m(const unsigned short* __restrict__ snb,
                                                const unsigned short* __restrict__ w1ab,
                                                const unsigned short* __restrict__ w3ab,
                                                const int* __restrict__ cnt,
                                                const int* __restrict__ list,
                                                float* __restrict__ t1,
                                                float* __restrict__ t3) {
  int tile = blockIdx.x, e = blockIdx.y, ks = blockIdx.z;
  int ni = cnt[e];
  if (tile * 16 >= ni) return;
  int l = threadIdx.x, lr = l & 15, lg = l >> 4;
  int slotA = tile * 16 + lr; if (slotA >= ni) slotA = ni - 1;
  int iA = list[e * Tt + slotA];
  const unsigned short* arow = snb + (size_t)(iA >> 1) * Dd + ks * 1024;
  const unsigned short* b1 = w1ab + ((size_t)e * 16 + lr) * Dd + ks * 1024;
  const unsigned short* b3 = w3ab + ((size_t)e * 16 + lr) * Dd + ks * 1024;
  f32x4 a1 = (f32x4){0.f,0.f,0.f,0.f}, a3 = (f32x4){0.f,0.f,0.f,0.f};
  #pragma unroll 4
  for (int k0 = 0; k0 < 1024; k0 += 32) {
    short8 af  = *(const short8*)(arow + k0 + lg * 8);
    short8 b1f = *(const short8*)(b1 + k0 + lg * 8);
    short8 b3f = *(const short8*)(b3 + k0 + lg * 8);
    a1 = mfma16x16(af, b1f, a1);
    a3 = mfma16x16(af, b3f, a3);
  }
  #pragma unroll
  for (int r = 0; r < 4; ++r) {
    int slot = tile * 16 + lg * 4 + r;
    if (slot < ni) {
      int i = list[e * Tt + slot];
      atomicAdd(&t1[(size_t)i * 16 + lr], a1[r]);
      atomicAdd(&t3[(size_t)i * 16 + lr], a3[r]);
    }
  }
}

// ---------- LoRA down via MFMA ----------
__global__ __launch_bounds__(64) void lora_down_m(const unsigned short* __restrict__ sr,
                                                  const unsigned short* __restrict__ w2ab,
                                                  const int* __restrict__ cnt,
                                                  const int* __restrict__ list,
                                                  float* __restrict__ t2) {
  int tile = blockIdx.x, e = blockIdx.y, ks = blockIdx.z;
  int ni = cnt[e];
  if (tile * 16 >= ni) return;
  int l = threadIdx.x, lr = l & 15, lg = l >> 4;
  int slotA = tile * 16 + lr; if (slotA >= ni) slotA = ni - 1;
  int iA = list[e * Tt + slotA];
  const unsigned short* arow = sr + (size_t)iA * Ff + ks * 1408;
  const unsigned short* brow = w2ab + ((size_t)e * 16 + lr) * Ff + ks * 1408;
  f32x4 acc = (f32x4){0.f,0.f,0.f,0.f};
  #pragma unroll 4
  for (int k0 = 0; k0 < 1408; k0 += 32) {
    short8 af = *(const short8*)(arow + k0 + lg * 8);
    short8 bf = *(const short8*)(brow + k0 + lg * 8);
    acc = mfma16x16(af, bf, acc);
  }
  #pragma unroll
  for (int r = 0; r < 4; ++r) {
    int slot = tile * 16 + lg * 4 + r;
    if (slot < ni) {
      int i = list[e * Tt + slot];
      atomicAdd(&t2[(size_t)i * 16 + lr], acc[r]);
    }
  }
}

// ---------- expert sr (reads fused c13 with stride F2) ----------
__global__ __launch_bounds__(256) void expert_sr_k(const unsigned short* __restrict__ c13,
                                                   const float* __restrict__ t1,
                                                   const float* __restrict__ t3,
                                                   const float* __restrict__ w1b,
                                                   const float* __restrict__ w3b,
                                                   const int* __restrict__ cnt,
                                                   const int* __restrict__ list,
                                                   unsigned short* __restrict__ sr) {
  int e = blockIdx.y;
  int f = blockIdx.x * 256 + threadIdx.x;
  __shared__ float W1[16 * 256], W3[16 * 256];
  #pragma unroll
  for (int r = 0; r < 16; ++r) {
    W1[r * 256 + threadIdx.x] = 2.0f * w1b[((size_t)e * Ff + f) * 16 + r];
    W3[r * 256 + threadIdx.x] = 2.0f * w3b[((size_t)e * Ff + f) * 16 + r];
  }
  __syncthreads();
  int n = cnt[e];
  int chunk = (n + 7) >> 3;
  int pbeg = blockIdx.z * chunk;
  int pend = min(n, pbeg + chunk);
  for (int p = pbeg; p < pend; ++p) {
    int i = list[e * Tt + p];
    int t = i >> 1;
    const float* u1 = t1 + (size_t)i * 16;
    const float* u3 = t3 + (size_t)i * 16;
    float l1 = 0.f, l3 = 0.f;
    #pragma unroll
    for (int r = 0; r < 16; ++r) {
      l1 += u1[r] * W1[r * 256 + threadIdx.x];
      l3 += u3[r] * W3[r * 256 + threadIdx.x];
    }
    float h1 = bf2f(c13[(size_t)t * F2 + f]) + l1;
    float h3 = bf2f(c13[(size_t)t * F2 + Ff + f]) + l3;
    float sv = (h1 / (1.f + __expf(-h1))) * h3;
    sr[(size_t)i * Ff + f] = f2bf(sv);
  }
}

// ---------- final combine (h = hb0 + hb1 split-K halves) ----------
__global__ __launch_bounds__(256) void combine_k(const float* __restrict__ hb0,
                                                 const float* __restrict__ hb1,
                                                 const float* __restrict__ t2,
                                                 const int* __restrict__ sel,
                                                 const float* __restrict__ ewt,
                                                 const float* __restrict__ w2b,
                                                 float* __restrict__ out) {
  int t = blockIdx.x;
  int d0 = threadIdx.x * 8;
  int e0 = sel[2 * t], e1 = sel[2 * t + 1];
  float a0 = ewt[2 * t], a1 = ewt[2 * t + 1];
  float uu0[16], uu1[16];
  const float* u0 = t2 + (size_t)(2 * t) * 16;
  const float* u1 = t2 + (size_t)(2 * t + 1) * 16;
  #pragma unroll
  for (int r = 0; r < 16; ++r) { uu0[r] = u0[r]; uu1[r] = u1[r]; }
  const float* wb0 = w2b + (size_t)e0 * Dd * 16;
  const float* wb1 = w2b + (size_t)e1 * Dd * 16;
  size_t r0 = (size_t)(2 * t) * Dd, r1 = (size_t)(2 * t + 1) * Dd;
  float* orow = out + (size_t)t * Dd;
  #pragma unroll
  for (int dd = 0; dd < 8; ++dd) {
    int d = d0 + dd;
    float l0 = 0.f, l1v = 0.f;
    #pragma unroll
    for (int r = 0; r < 16; ++r) {
      l0  += uu0[r] * wb0[(size_t)d * 16 + r];
      l1v += uu1[r] * wb1[(size_t)d * 16 + r];
    }
    float h0 = hb0[r0 + d] + hb1[r0 + d];
    float h1 = hb0[r1 + d] + hb1[r1 + d];
    orow[d] += a0 * (h0 + 2.f * l0) + a1 * (h1 + 2.f * l1v);
  }
}

// ---------- launch ----------
extern "C" void kernel_launch(void* const* d_in, const int* in_sizes, int n_in,
                              void* d_out, int out_size, void* d_ws, size_t ws_size,
                              hipStream_t stream) {
  const float* data  = (const float*)d_in[0];
  const float* mask  = (const float*)d_in[1];
  const float* ropec = (const float*)d_in[2];
  const float* ropes = (const float*)d_in[3];
  const float* anw   = (const float*)d_in[4];
  const float* fnw   = (const float*)d_in[5];
  const float* wq_f  = (const float*)d_in[6];
  const float* wk_f  = (const float*)d_in[7];
  const float* wv_f  = (const float*)d_in[8];
  const float* wo_f  = (const float*)d_in[9];
  const float* gate  = (const float*)d_in[10];
  const float* w1_f  = (const float*)d_in[11];
  const float* w2_f  = (const float*)d_in[12];
  const float* w3_f  = (const float*)d_in[13];
  const float* w1a   = (const float*)d_in[14];
  const float* w1bl  = (const float*)d_in[15];
  const float* w3a   = (const float*)d_in[16];
  const float* w3bl  = (const float*)d_in[17];
  const float* w2a   = (const float*)d_in[18];
  const float* w2bl  = (const float*)d_in[19];
  float* out = (float*)d_out;

  char* base = (char*)d_ws;
  size_t off = 0;
  auto take = [&](size_t bytes) -> char* {
    char* r = base + off;
    off += (bytes + 255) & ~(size_t)255;
    return r;
  };
  unsigned short* wqh = (unsigned short*)take((size_t)Dd * Dd * 2);
  unsigned short* wql = (unsigned short*)take((size_t)Dd * Dd * 2);
  unsigned short* wkh = (unsigned short*)take((size_t)NKV * Dd * 2);
  unsigned short* wkl = (unsigned short*)take((size_t)NKV * Dd * 2);
  unsigned short* wvh = (unsigned short*)take((size_t)NKV * Dd * 2);
  unsigned short* wvl = (unsigned short*)take((size_t)NKV * Dd * 2);
  unsigned short* woh = (unsigned short*)take((size_t)Dd * Dd * 2);
  unsigned short* wol = (unsigned short*)take((size_t)Dd * Dd * 2);
  unsigned short* w13bf = (unsigned short*)take((size_t)F2 * Dd * 2);  // w1 | w3 stacked
  unsigned short* w2bf  = (unsigned short*)take((size_t)Dd * Ff * 2);
  unsigned short* xh = (unsigned short*)take((size_t)Tt * Dd * 2);
  unsigned short* xl = (unsigned short*)take((size_t)Tt * Dd * 2);
  unsigned short* qhB = (unsigned short*)take((size_t)Tt * Dd * 2);
  unsigned short* qlB = (unsigned short*)take((size_t)Tt * Dd * 2);
  unsigned short* khB = (unsigned short*)take((size_t)Tt * NKV * 2);
  unsigned short* klB = (unsigned short*)take((size_t)Tt * NKV * 2);
  unsigned short* vhB = (unsigned short*)take((size_t)Tt * NKV * 2);
  unsigned short* vlB = (unsigned short*)take((size_t)Tt * NKV * 2);
  unsigned short* srb = (unsigned short*)take((size_t)M2 * Ff * 2);
  float* hb = (float*)take((size_t)M2 * Dd * 4);          // early: fused qkv f32 [Tt][4096]
  float* t1b = (float*)take((size_t)M2 * 16 * 4);
  float* t3b = (float*)take((size_t)M2 * 16 * 4);
  float* t2b = (float*)take((size_t)M2 * 16 * 4);
  int*   selb = (int*)take((size_t)M2 * 4);
  float* ewtb = (float*)take((size_t)M2 * 4);
  float* logitsb = (float*)take((size_t)Tt * 8 * 4);
  float* mzb = (float*)take((size_t)16 * 2 * 4);
  int*   cntb = (int*)take(8 * 4);
  int*   listb = (int*)take((size_t)8 * Tt * 4);
  unsigned short* w1ab = (unsigned short*)take((size_t)Ee * Rr * Dd * 2);
  unsigned short* w3ab = (unsigned short*)take((size_t)Ee * Rr * Dd * 2);
  unsigned short* w2ab = (unsigned short*)take((size_t)Ee * Rr * Ff * 2);
  if (off > ws_size) return;

  // time-disjoint aliases
  float* qkv = (float*)hb;                        // Tt x 4096 f32
  unsigned short* aoh = xh;
  unsigned short* aol = xl;
  unsigned short* snb = qhB;
  unsigned short* c13b = wqh;                     // 46.1 MB spans wqh..wol (dead weights)
  float* hb1 = (float*)xh;                        // 33.5 MB spans xh..qlB (dead by h-GEMM)

  // weight casts
  cast_split_w<<<2048, 256, 0, stream>>>(wq_f, wqh, wql, Dd * Dd);
  cast_split_w<<<1024, 256, 0, stream>>>(wk_f, wkh, wkl, NKV * Dd);
  cast_split_w<<<1024, 256, 0, stream>>>(wv_f, wvh, wvl, NKV * Dd);
  cast_split_w<<<2048, 256, 0, stream>>>(wo_f, woh, wol, Dd * Dd);
  cast_w<<<5632, 256, 0, stream>>>(w1_f, w13bf, Ff * Dd);
  cast_w<<<5632, 256, 0, stream>>>(w3_f, w13bf + (size_t)Ff * Dd, Ff * Dd);
  cast_w<<<5632, 256, 0, stream>>>(w2_f, w2bf, Dd * Ff);
  cast_w<<<128, 256, 0, stream>>>(w1a, w1ab, Ee * Rr * Dd);
  cast_w<<<128, 256, 0, stream>>>(w3a, w3ab, Ee * Rr * Dd);
  cast_w<<<352, 256, 0, stream>>>(w2a, w2ab, Ee * Rr * Ff);
  zero_f32<<<768, 256, 0, stream>>>(t1b, 3 * M2 * 16);   // t1b,t3b,t2b contiguous

  // attention block
  rmsnorm_split_k<<<Tt, 256, 0, stream>>>(data, anw, xh, xl);
  gemm3_v3<1, 1><<<512, 512, 0, stream>>>(xh, xl, wqh, wql, wkh, wkl, wvh, wvl,
                                          Dd, Dd + NKV, qkv, nullptr, Tt, NQKV, Dd, 32);
  vsplit_k<<<Tt, 128, 0, stream>>>(qkv, vhB, vlB);
  rope_split_k<<<Tt, 256, 0, stream>>>(qkv, NQKV, ropec, ropes, qhB, qlB, Hh);
  rope_split_k<<<Tt, 128, 0, stream>>>(qkv + Dd, NQKV, ropec, ropes, khB, klB, HKVv);
  attn3_k<<<dim3(16, 32), 256, 0, stream>>>(qhB, qlB, khB, klB, vhB, vlB, mask, aoh, aol);
  gemm3_v3<2, 1><<<256, 512, 0, stream>>>(aoh, aol, woh, wol, woh, wol, woh, wol,
                                          Dd, Dd, d_out, data, Tt, Dd, Dd, 16);

  // FFN block
  rmsnorm_k<<<Tt, 256, 0, stream>>>(out, fnw, snb);
  router_logits<<<512, 256, 0, stream>>>(out, fnw, gate, logitsb);
  router_colstats<<<16, 256, 0, stream>>>(logitsb, mzb);
  router_select<<<8, 256, 0, stream>>>(logitsb, mzb, selb, ewtb);
  zero_cnt_k<<<1, 64, 0, stream>>>(cntb);
  gather_k<<<16, 256, 0, stream>>>(selb, cntb, listb);
  // fused c1|c3: N=11264, 1408 blocks, B-stationary (colmaj) for L2 reuse
  gemm_bt64_v3<0, 1><<<1408, 512, 0, stream>>>(snb, w13bf, c13b, nullptr, Tt, F2, Dd, Dd, 88);
  lora_up_m<<<dim3(128, 8, 2), 64, 0, stream>>>(snb, w1ab, w3ab, cntb, listb, t1b, t3b);
  expert_sr_k<<<dim3(22, 8, 8), 256, 0, stream>>>(c13b, t1b, t3b, w1bl, w3bl, cntb, listb, srb);
  lora_down_m<<<dim3(128, 8, 4), 64, 0, stream>>>(srb, w2ab, cntb, listb, t2b);
  // h split-K=2: 1024 blocks, row-major (A-panel-stationary); slice0 -> hb, slice1 -> hb1
  gemm_bt64_v3<1, 0><<<1024, 512, 0, stream>>>(srb, w2bf, hb, hb1, M2, Dd, Ff / 2, Ff, 16);
  combine_k<<<Tt, 256, 0, stream>>>(hb, hb1, t2b, selb, ewtb, w2bl, out);
}

// Round 14
// 878.927 us; speedup vs baseline: 1.0194x; 1.0194x over previous
//
#include <hip/hip_runtime.h>
#include <hip/hip_bf16.h>
#include <stdint.h>

#define DEVI __device__ __forceinline__

typedef __attribute__((ext_vector_type(8))) short short8;
typedef __attribute__((ext_vector_type(4))) short short4b;
typedef __attribute__((ext_vector_type(4))) float f32x4;

constexpr int Bb  = 2, Ss = 1024, Dd = 2048, Hh = 16, HKVv = 8, HDd = 128;
constexpr int Ff  = 5632, Ee = 8, Rr = 16;
constexpr int Tt  = Bb * Ss;        // 2048 tokens
constexpr int M2  = 2 * Tt;         // 4096 (token,slot) rows
constexpr int NKV = HKVv * HDd;     // 1024
constexpr int NQKV = Dd + 2 * NKV;  // 4096 fused qkv width
constexpr int F2  = 2 * Ff;         // 11264 fused c1|c3 width

// ---------- small helpers ----------
DEVI unsigned short f2bf(float f) {
  union { float f; unsigned u; } x; x.f = f;
  unsigned r = (x.u + 0x7FFFu + ((x.u >> 16) & 1u)) >> 16;
  return (unsigned short)r;
}
DEVI float bf2f(unsigned short h) {
  union { unsigned u; float f; } x; x.u = ((unsigned)h) << 16; return x.f;
}
DEVI float wsum64(float v) {
  #pragma unroll
  for (int d = 1; d < 64; d <<= 1) v += __shfl_xor(v, d, 64);
  return v;
}
DEVI float wsum16(float v) {
  v += __shfl_xor(v, 1, 64); v += __shfl_xor(v, 2, 64);
  v += __shfl_xor(v, 4, 64); v += __shfl_xor(v, 8, 64);
  return v;
}
DEVI float wmax16(float v) {
  v = fmaxf(v, __shfl_xor(v, 1, 64)); v = fmaxf(v, __shfl_xor(v, 2, 64));
  v = fmaxf(v, __shfl_xor(v, 4, 64)); v = fmaxf(v, __shfl_xor(v, 8, 64));
  return v;
}
typedef __attribute__((address_space(1))) void gvoid;
typedef __attribute__((address_space(3))) void lvoid;
DEVI void gl_lds16(const void* g, void* l) {
  __builtin_amdgcn_global_load_lds((gvoid*)g, (lvoid*)l, 16, 0, 0);
}
DEVI unsigned ldsoff(const void* p) {
  return (unsigned)(uintptr_t)(lvoid*)p;
}
DEVI f32x4 mfma16x16(short8 a, short8 b, f32x4 c) {
  return __builtin_amdgcn_mfma_f32_16x16x32_bf16(a, b, c, 0, 0, 0);
}
DEVI void cast8(const float* src, unsigned short* dst, size_t i) {
  const float4* p = (const float4*)(src + i);
  float4 a = p[0], b = p[1];
  float v[8] = {a.x,a.y,a.z,a.w,b.x,b.y,b.z,b.w};
  short8 o;
  #pragma unroll
  for (int j = 0; j < 8; ++j) o[j] = (short)f2bf(v[j]);
  *(short8*)(dst + i) = o;
}
DEVI void csplit8(const float* src, unsigned short* dh, unsigned short* dl, size_t i) {
  const float4* p = (const float4*)(src + i);
  float4 a = p[0], b = p[1];
  float v[8] = {a.x,a.y,a.z,a.w,b.x,b.y,b.z,b.w};
  short8 h, l;
  #pragma unroll
  for (int j = 0; j < 8; ++j) {
    unsigned short hb = f2bf(v[j]);
    h[j] = (short)hb;
    l[j] = (short)f2bf(v[j] - bf2f(hb));
  }
  *(short8*)(dh + i) = h;
  *(short8*)(dl + i) = l;
}
// rope 8 contiguous elems (4 pairs) from f32 src -> split pair
DEVI void rope8(const float* src, const float* cr, const float* sr,
                unsigned short* oh, unsigned short* ol) {
  const float4* px = (const float4*)src;
  float4 a = px[0], b = px[1];
  float vv[8] = {a.x,a.y,a.z,a.w,b.x,b.y,b.z,b.w};
  short8 hs, ls;
  #pragma unroll
  for (int p = 0; p < 4; ++p) {
    float x1 = vv[2 * p], x2 = vv[2 * p + 1];
    float c = cr[p], si = sr[p];
    float o1 = x1 * c - x2 * si;
    float o2 = x1 * si + x2 * c;
    unsigned short h1 = f2bf(o1), h2 = f2bf(o2);
    hs[2 * p] = (short)h1;      hs[2 * p + 1] = (short)h2;
    ls[2 * p] = (short)f2bf(o1 - bf2f(h1));
    ls[2 * p + 1] = (short)f2bf(o2 - bf2f(h2));
  }
  *(short8*)oh = hs;
  *(short8*)ol = ls;
}

// ---------- fused plain casts: 6 segments (w1,w3 -> w13bf | w2 | w1a | w3a | w2a) ----------
__global__ __launch_bounds__(256) void cast_all6(const float* __restrict__ w1f,
                                                 const float* __restrict__ w3f,
                                                 const float* __restrict__ w2f,
                                                 const float* __restrict__ w1a,
                                                 const float* __restrict__ w3a,
                                                 const float* __restrict__ w2a,
                                                 unsigned short* __restrict__ w13,
                                                 unsigned short* __restrict__ w2b,
                                                 unsigned short* __restrict__ w1ab,
                                                 unsigned short* __restrict__ w3ab,
                                                 unsigned short* __restrict__ w2ab) {
  int b = blockIdx.x;
  const float* src; unsigned short* dst;
  if (b < 5632)       { src = w1f; dst = w13; }
  else if (b < 11264) { src = w3f; dst = w13 + (size_t)Ff * Dd; b -= 5632; }
  else if (b < 16896) { src = w2f; dst = w2b;  b -= 11264; }
  else if (b < 17024) { src = w1a; dst = w1ab; b -= 16896; }
  else if (b < 17152) { src = w3a; dst = w3ab; b -= 17024; }
  else                { src = w2a; dst = w2ab; b -= 17152; }
  cast8(src, dst, ((size_t)b * 256 + threadIdx.x) * 8);
}

// ---------- fused split casts: 4 segments (wq | wk | wv | wo) ----------
__global__ __launch_bounds__(256) void cast_split4(const float* __restrict__ wq,
                                                   const float* __restrict__ wk,
                                                   const float* __restrict__ wv,
                                                   const float* __restrict__ wo,
                                                   unsigned short* __restrict__ qh_,
                                                   unsigned short* __restrict__ ql_,
                                                   unsigned short* __restrict__ kh_,
                                                   unsigned short* __restrict__ kl_,
                                                   unsigned short* __restrict__ vh_,
                                                   unsigned short* __restrict__ vl_,
                                                   unsigned short* __restrict__ oh_,
                                                   unsigned short* __restrict__ ol_) {
  int b = blockIdx.x;
  const float* src; unsigned short* dh; unsigned short* dl;
  if (b < 2048)      { src = wq; dh = qh_; dl = ql_; }
  else if (b < 3072) { src = wk; dh = kh_; dl = kl_; b -= 2048; }
  else if (b < 4096) { src = wv; dh = vh_; dl = vl_; b -= 3072; }
  else               { src = wo; dh = oh_; dl = ol_; b -= 4096; }
  csplit8(src, dh, dl, ((size_t)b * 256 + threadIdx.x) * 8);
}

__global__ __launch_bounds__(256) void zero_f32(float* __restrict__ p, int n) {
  int i = blockIdx.x * 256 + threadIdx.x;
  if (i < n) p[i] = 0.f;
}

// ---------- rmsnorm f32 -> single bf16 ----------
__global__ __launch_bounds__(256) void rmsnorm_k(const float* __restrict__ x,
                                                 const float* __restrict__ w,
                                                 unsigned short* __restrict__ out) {
  int row = blockIdx.x, tid = threadIdx.x;
  const float* xr = x + (size_t)row * Dd;
  const float4* p4 = (const float4*)(xr + tid * 8);
  float4 a = p4[0], b = p4[1];
  float v[8] = {a.x,a.y,a.z,a.w,b.x,b.y,b.z,b.w};
  float ss = 0.f;
  #pragma unroll
  for (int j = 0; j < 8; ++j) ss += v[j] * v[j];
  ss = wsum64(ss);
  __shared__ float red[4];
  int wv_ = tid >> 6, l = tid & 63;
  if (l == 0) red[wv_] = ss;
  __syncthreads();
  float tot = red[0] + red[1] + red[2] + red[3];
  float rstd = rsqrtf(tot * (1.0f / Dd) + 1e-5f);
  const float* wr = w + tid * 8;
  short8 o;
  #pragma unroll
  for (int j = 0; j < 8; ++j) o[j] = (short)f2bf(v[j] * rstd * wr[j]);
  *(short8*)(out + (size_t)row * Dd + tid * 8) = o;
}

// ---------- rmsnorm f32 -> split bf16 pair ----------
__global__ __launch_bounds__(256) void rmsnorm_split_k(const float* __restrict__ x,
                                                       const float* __restrict__ w,
                                                       unsigned short* __restrict__ outh,
                                                       unsigned short* __restrict__ outl) {
  int row = blockIdx.x, tid = threadIdx.x;
  const float* xr = x + (size_t)row * Dd;
  const float4* p4 = (const float4*)(xr + tid * 8);
  float4 a = p4[0], b = p4[1];
  float v[8] = {a.x,a.y,a.z,a.w,b.x,b.y,b.z,b.w};
  float ss = 0.f;
  #pragma unroll
  for (int j = 0; j < 8; ++j) ss += v[j] * v[j];
  ss = wsum64(ss);
  __shared__ float red[4];
  int wv_ = tid >> 6, l = tid & 63;
  if (l == 0) red[wv_] = ss;
  __syncthreads();
  float tot = red[0] + red[1] + red[2] + red[3];
  float rstd = rsqrtf(tot * (1.0f / Dd) + 1e-5f);
  const float* wr = w + tid * 8;
  short8 oh, ol;
  #pragma unroll
  for (int j = 0; j < 8; ++j) {
    float val = v[j] * rstd * wr[j];
    unsigned short hb = f2bf(val);
    oh[j] = (short)hb;
    ol[j] = (short)f2bf(val - bf2f(hb));
  }
  *(short8*)(outh + (size_t)row * Dd + tid * 8) = oh;
  *(short8*)(outl + (size_t)row * Dd + tid * 8) = ol;
}

// ---------- bf16 GEMM v4: 8-wave/512-thread, BK=64, XOR LDS, acc 2x4, 2-phase dbuf ----------
// COLMAJ=1: by varies fastest (B-panel-stationary). ks only when COLMAJ=0.
template <int MODE, int COLMAJ>
__global__ __launch_bounds__(512) void gemm_bt64_v4(const unsigned short* __restrict__ A,
                                                    const unsigned short* __restrict__ Bw,
                                                    void* __restrict__ C0,
                                                    void* __restrict__ C1,
                                                    int M, int N, int Kext, int ld, int gx) {
  __shared__ __align__(16) unsigned short As[2][128 * 64];
  __shared__ __align__(16) unsigned short Bs[2][128 * 64];
  int tid = threadIdx.x;
  int w = tid >> 6, l = tid & 63;
  int lr = l & 15, lg = l >> 4;
  int cpx = (int)gridDim.x >> 3;
  int bid = blockIdx.x;
  int swz = (bid & 7) * cpx + (bid >> 3);
  int mtiles = M >> 7;
  int bx, by, ks = 0;
  if (COLMAJ) { by = swz % mtiles; bx = swz / mtiles; }
  else {
    bx = swz % gx; by = swz / gx;
    if (by >= mtiles) { ks = 1; by -= mtiles; }
  }
  int m0 = by * 128, n0 = bx * 128;
  int koff = ks * Kext;
  int wr = (w >> 1) * 32, wc = (w & 1) * 64;
  f32x4 acc[2][4];
  #pragma unroll
  for (int i = 0; i < 2; ++i)
    #pragma unroll
    for (int j = 0; j < 4; ++j) acc[i][j] = (f32x4){0.f, 0.f, 0.f, 0.f};

  int srow = w * 16 + (l >> 3);
  int schunk = (l & 7) ^ (l >> 3);
  const unsigned short* ga = A  + (size_t)(m0 + srow) * ld + koff + schunk * 8;
  const unsigned short* gb = Bw + (size_t)(n0 + srow) * ld + koff + schunk * 8;

  auto STAGE = [&](int b, int k0) {
    #pragma unroll
    for (int c = 0; c < 2; ++c) {
      gl_lds16(ga + k0 + (size_t)(c * 8) * ld, As[b] + w * 1024 + c * 512);
      gl_lds16(gb + k0 + (size_t)(c * 8) * ld, Bs[b] + w * 1024 + c * 512);
    }
  };
  auto COMP = [&](int b) {
    #pragma unroll
    for (int kk = 0; kk < 2; ++kk) {
      int rc = ((kk * 4 + lg) ^ (lr & 7)) * 8;
      short8 af[2], bfr[4];
      #pragma unroll
      for (int i = 0; i < 2; ++i)
        af[i]  = *(const short8*)(As[b] + (wr + i * 16 + lr) * 64 + rc);
      #pragma unroll
      for (int j = 0; j < 4; ++j)
        bfr[j] = *(const short8*)(Bs[b] + (wc + j * 16 + lr) * 64 + rc);
      #pragma unroll
      for (int i = 0; i < 2; ++i)
        #pragma unroll
        for (int j = 0; j < 4; ++j) acc[i][j] = mfma16x16(af[i], bfr[j], acc[i][j]);
    }
  };

  int nk = Kext >> 6;
  STAGE(0, 0);
  __syncthreads();
  int cur = 0;
  for (int kt = 0; kt < nk - 1; ++kt) {
    STAGE(cur ^ 1, (kt + 1) << 6);
    COMP(cur);
    __syncthreads();
    cur ^= 1;
  }
  COMP(cur);

  float* Cf = (float*)(ks ? C1 : C0);
  #pragma unroll
  for (int i = 0; i < 2; ++i)
    #pragma unroll
    for (int j = 0; j < 4; ++j) {
      int m = m0 + wr + i * 16 + lg * 4;
      int n = n0 + wc + j * 16 + lr;
      #pragma unroll
      for (int r = 0; r < 4; ++r) {
        float vv = acc[i][j][r];
        size_t o = (size_t)(m + r) * N + n;
        if (MODE == 0) ((unsigned short*)C0)[o] = f2bf(vv);
        else           Cf[o] = vv;
      }
    }
}

// ---------- 3-pass split-bf16 GEMM v4: 8-wave/512-thread, BK=32, swizzle v2, 2-phase dbuf ----------
template <int MODE, int COLMAJ>
__global__ __launch_bounds__(512) void gemm3_v4(const unsigned short* __restrict__ Ah,
                                                const unsigned short* __restrict__ Al,
                                                const unsigned short* __restrict__ Bh1,
                                                const unsigned short* __restrict__ Bl1,
                                                const unsigned short* __restrict__ Bh2,
                                                const unsigned short* __restrict__ Bl2,
                                                const unsigned short* __restrict__ Bh3,
                                                const unsigned short* __restrict__ Bl3,
                                                int nsplit1, int nsplit2,
                                                void* __restrict__ C0,
                                                const float* __restrict__ resid,
                                                int M, int N, int K, int gx) {
  __shared__ __align__(16) unsigned short Ash[2][128 * 32];
  __shared__ __align__(16) unsigned short Asl[2][128 * 32];
  __shared__ __align__(16) unsigned short Bsh[2][128 * 32];
  __shared__ __align__(16) unsigned short Bsl[2][128 * 32];
  int tid = threadIdx.x;
  int w = tid >> 6, l = tid & 63;
  int lr = l & 15, lg = l >> 4;
  int cpx = (int)gridDim.x >> 3;
  int bid = blockIdx.x;
  int swz = (bid & 7) * cpx + (bid >> 3);
  int mtiles = M >> 7;
  int bx, by;
  if (COLMAJ) { by = swz % mtiles; bx = swz / mtiles; }
  else        { bx = swz % gx;     by = swz / gx; }
  int m0 = by * 128, n0 = bx * 128;
  int wr = (w >> 1) * 32, wc = (w & 1) * 64;

  const unsigned short* Bh; const unsigned short* Bl; int nb;
  if (n0 < nsplit1)      { Bh = Bh1; Bl = Bl1; nb = n0; }
  else if (n0 < nsplit2) { Bh = Bh2; Bl = Bl2; nb = n0 - nsplit1; }
  else                   { Bh = Bh3; Bl = Bl3; nb = n0 - nsplit2; }

  f32x4 acc[2][4];
  #pragma unroll
  for (int i = 0; i < 2; ++i)
    #pragma unroll
    for (int j = 0; j < 4; ++j) acc[i][j] = (f32x4){0.f, 0.f, 0.f, 0.f};

  int srow = w * 16 + (l >> 2);
  int scol = ((l & 3) ^ ((l >> 3) & 3)) * 8;
  const unsigned short* gah = Ah + (size_t)(m0 + srow) * K + scol;
  const unsigned short* gal = Al + (size_t)(m0 + srow) * K + scol;
  const unsigned short* gbh = Bh + (size_t)(nb + srow) * K + scol;
  const unsigned short* gbl = Bl + (size_t)(nb + srow) * K + scol;

  auto STAGE = [&](int b, int k0) {
    gl_lds16(gah + k0, Ash[b] + w * 512);
    gl_lds16(gal + k0, Asl[b] + w * 512);
    gl_lds16(gbh + k0, Bsh[b] + w * 512);
    gl_lds16(gbl + k0, Bsl[b] + w * 512);
  };
  auto COMP = [&](int b) {
    int rc = (lg ^ ((lr >> 1) & 3)) * 8;
    short8 afh[2], afl[2], bfh[4], bfl[4];
    #pragma unroll
    for (int i = 0; i < 2; ++i) {
      afh[i] = *(const short8*)(Ash[b] + (wr + i * 16 + lr) * 32 + rc);
      afl[i] = *(const short8*)(Asl[b] + (wr + i * 16 + lr) * 32 + rc);
    }
    #pragma unroll
    for (int j = 0; j < 4; ++j) {
      bfh[j] = *(const short8*)(Bsh[b] + (wc + j * 16 + lr) * 32 + rc);
      bfl[j] = *(const short8*)(Bsl[b] + (wc + j * 16 + lr) * 32 + rc);
    }
    #pragma unroll
    for (int i = 0; i < 2; ++i)
      #pragma unroll
      for (int j = 0; j < 4; ++j) {
        acc[i][j] = mfma16x16(afh[i], bfh[j], acc[i][j]);
        acc[i][j] = mfma16x16(afh[i], bfl[j], acc[i][j]);
        acc[i][j] = mfma16x16(afl[i], bfh[j], acc[i][j]);
      }
  };

  int nk = K >> 5;
  STAGE(0, 0);
  __syncthreads();
  int cur = 0;
  for (int kt = 0; kt < nk - 1; ++kt) {
    STAGE(cur ^ 1, (kt + 1) << 5);
    COMP(cur);
    __syncthreads();
    cur ^= 1;
  }
  COMP(cur);

  #pragma unroll
  for (int i = 0; i < 2; ++i)
    #pragma unroll
    for (int j = 0; j < 4; ++j) {
      int m = m0 + wr + i * 16 + lg * 4;
      int n = n0 + wc + j * 16 + lr;
      #pragma unroll
      for (int r = 0; r < 4; ++r) {
        float vv = acc[i][j][r];
        size_t o = (size_t)(m + r) * N + n;
        if (MODE == 1) ((float*)C0)[o] = vv;
        else           ((float*)C0)[o] = vv + resid[o];
      }
    }
}

// ---------- fused rope(q) + rope(k) + vsplit, one launch (512 threads, wave-aligned roles) ----------
__global__ __launch_bounds__(512) void rope_vsplit_k(const float* __restrict__ qkv,
                                                     const float* __restrict__ cs,
                                                     const float* __restrict__ sn,
                                                     unsigned short* __restrict__ qh_,
                                                     unsigned short* __restrict__ ql_,
                                                     unsigned short* __restrict__ kh_,
                                                     unsigned short* __restrict__ kl_,
                                                     unsigned short* __restrict__ vh_,
                                                     unsigned short* __restrict__ vl_) {
  int row = blockIdx.x;
  int s = row & (Ss - 1);
  int tid = threadIdx.x;
  const float* base = qkv + (size_t)row * NQKV;
  if (tid < 256) {            // q rope: 2048 elems
    int bas = tid * 8;
    int d = bas & (HDd - 1);
    rope8(base + bas, cs + s * 64 + (d >> 1), sn + s * 64 + (d >> 1),
          qh_ + (size_t)row * Dd + bas, ql_ + (size_t)row * Dd + bas);
  } else if (tid < 384) {     // k rope: 1024 elems
    int bas = (tid - 256) * 8;
    int d = bas & (HDd - 1);
    rope8(base + Dd + bas, cs + s * 64 + (d >> 1), sn + s * 64 + (d >> 1),
          kh_ + (size_t)row * NKV + bas, kl_ + (size_t)row * NKV + bas);
  } else {                    // v split-cast: 1024 elems
    int bas = (tid - 384) * 8;
    const float4* p = (const float4*)(base + Dd + NKV + bas);
    float4 a = p[0], b = p[1];
    float v[8] = {a.x,a.y,a.z,a.w,b.x,b.y,b.z,b.w};
    short8 h, l;
    #pragma unroll
    for (int j = 0; j < 8; ++j) {
      unsigned short hb = f2bf(v[j]);
      h[j] = (short)hb;
      l[j] = (short)f2bf(v[j] - bf2f(hb));
    }
    size_t o = (size_t)row * NKV + bas;
    *(short8*)(vh_ + o) = h;
    *(short8*)(vl_ + o) = l;
  }
}

// ---------- flash attention, 3-pass split precision ----------
__global__ __launch_bounds__(256) void attn3_k(const unsigned short* __restrict__ qh,
                                               const unsigned short* __restrict__ ql,
                                               const unsigned short* __restrict__ kh,
                                               const unsigned short* __restrict__ kl,
                                               const unsigned short* __restrict__ vh,
                                               const unsigned short* __restrict__ vl,
                                               const float* __restrict__ mask,
                                               unsigned short* __restrict__ aoh,
                                               unsigned short* __restrict__ aol) {
  __shared__ __align__(16) unsigned short Ksh[32 * 128], Ksl[32 * 128];
  __shared__ __align__(16) unsigned short VTh[8 * 528], VTl[8 * 528];
  __shared__ __align__(16) unsigned short Plh[4 * 16 * 40], Pll[4 * 16 * 40];
  int tid = threadIdx.x, w = tid >> 6, l = tid & 63;
  int lr = l & 15, lg = l >> 4;
  int b = blockIdx.y >> 4, h = blockIdx.y & 15, hk = h >> 1;
  int q0 = blockIdx.x * 64 + w * 16;

  short8 qfh[4], qfl[4];
  {
    size_t qoff = ((size_t)(b * Ss + q0 + lr)) * Dd;
    #pragma unroll
    for (int ds = 0; ds < 4; ++ds) {
      qfh[ds] = *(const short8*)(qh + qoff + h * HDd + ds * 32 + lg * 8);
      qfl[ds] = *(const short8*)(ql + qoff + h * HDd + ds * 32 + lg * 8);
    }
  }

  float mreg[4] = {-1e30f, -1e30f, -1e30f, -1e30f};
  float lreg[4] = {0.f, 0.f, 0.f, 0.f};
  f32x4 oacc[8];
  #pragma unroll
  for (int db = 0; db < 8; ++db) oacc[db] = (f32x4){0.f, 0.f, 0.f, 0.f};

  const float sc = 0.08838834764831845f;  // 1/sqrt(128)
  size_t kvbase = ((size_t)(b * Ss)) * NKV + hk * HDd;
  const unsigned short* kb_h = kh + kvbase;
  const unsigned short* kb_l = kl + kvbase;
  const unsigned short* vb_h = vh + kvbase;
  const unsigned short* vb_l = vl + kvbase;

  int kc1 = (lr ^ lg) * 8;
  int kc2 = (lr ^ (lg + 4)) * 8;
  int vrow_a = w * 8 + ((l & 7) >> 1);
  int vchunk = ((l >> 3) * 2 + (l & 1)) * 8;
  unsigned short* vh1 = VTh + (2 * w) * 528;
  unsigned short* vh2 = VTh + (2 * w + 1) * 528;
  unsigned short* vl1 = VTl + (2 * w) * 528;
  unsigned short* vl2 = VTl + (2 * w + 1) * 528;
  unsigned vtbh = ldsoff(VTh) + (unsigned)lr * 8u;
  unsigned vtbl = ldsoff(VTl) + (unsigned)lr * 8u;

  for (int kv0 = 0; kv0 < Ss; kv0 += 32) {
    int r1 = kv0 + w * 8 + lg;
    gl_lds16(kb_h + (size_t)r1 * NKV + kc1,       Ksh + w * 1024);
    gl_lds16(kb_h + (size_t)(r1 + 4) * NKV + kc2, Ksh + w * 1024 + 512);
    gl_lds16(kb_l + (size_t)r1 * NKV + kc1,       Ksl + w * 1024);
    gl_lds16(kb_l + (size_t)(r1 + 4) * NKV + kc2, Ksl + w * 1024 + 512);
    int vr0 = kv0 + vrow_a;
    gl_lds16(vb_h + (size_t)vr0 * NKV + vchunk,       vh1);
    gl_lds16(vb_h + (size_t)(vr0 + 4) * NKV + vchunk, vh2);
    gl_lds16(vb_l + (size_t)vr0 * NKV + vchunk,       vl1);
    gl_lds16(vb_l + (size_t)(vr0 + 4) * NKV + vchunk, vl2);
    __syncthreads();

    f32x4 s0 = (f32x4){0.f,0.f,0.f,0.f}, s1 = (f32x4){0.f,0.f,0.f,0.f};
    #pragma unroll
    for (int ds = 0; ds < 4; ++ds) {
      int kcol = ((ds * 4 + lg) ^ (lr & 7)) * 8;
      short8 kh0 = *(const short8*)(Ksh + lr * 128 + kcol);
      short8 kh1 = *(const short8*)(Ksh + (16 + lr) * 128 + kcol);
      short8 kl0 = *(const short8*)(Ksl + lr * 128 + kcol);
      short8 kl1 = *(const short8*)(Ksl + (16 + lr) * 128 + kcol);
      s0 = mfma16x16(qfh[ds], kh0, s0);
      s0 = mfma16x16(qfh[ds], kl0, s0);
      s0 = mfma16x16(qfl[ds], kh0, s0);
      s1 = mfma16x16(qfh[ds], kh1, s1);
      s1 = mfma16x16(qfh[ds], kl1, s1);
      s1 = mfma16x16(qfl[ds], kh1, s1);
    }
    const float* mrow = mask + (size_t)(q0 + lg * 4) * Ss + kv0 + lr;
    #pragma unroll
    for (int r = 0; r < 4; ++r) {
      float a0 = s0[r] * sc + mrow[(size_t)r * Ss];
      float a1 = s1[r] * sc + mrow[(size_t)r * Ss + 16];
      float t = wmax16(fmaxf(a0, a1));
      float mn = fmaxf(mreg[r], t);
      float resc = __expf(mreg[r] - mn);
      mreg[r] = mn;
      float e0 = __expf(a0 - mn), e1 = __expf(a1 - mn);
      float ps = wsum16(e0 + e1);
      lreg[r] = lreg[r] * resc + ps;
      #pragma unroll
      for (int db = 0; db < 8; ++db) oacc[db][r] *= resc;
      unsigned short h0 = f2bf(e0), h1 = f2bf(e1);
      unsigned short* prowh = Plh + (w * 16 + lg * 4 + r) * 40;
      unsigned short* prowl = Pll + (w * 16 + lg * 4 + r) * 40;
      prowh[lr] = h0;            prowh[16 + lr] = h1;
      prowl[lr] = f2bf(e0 - bf2f(h0));
      prowl[16 + lr] = f2bf(e1 - bf2f(h1));
    }
    asm volatile("" ::: "memory");
    short8 pfh = *(const short8*)(Plh + (w * 16 + lr) * 40 + lg * 8);
    short8 pfl = *(const short8*)(Pll + (w * 16 + lr) * 40 + lg * 8);

    short4b v4[16];
    #pragma unroll
    for (int db = 0; db < 8; ++db) {
      #pragma unroll
      for (int t = 0; t < 2; ++t) {
        unsigned off = vtbh + (unsigned)((lg * 2 + t) * 1056 + db * 128);
        asm volatile("ds_read_b64_tr_b16 %0, %1" : "=v"(v4[db * 2 + t]) : "v"(off));
      }
    }
    asm volatile("s_waitcnt lgkmcnt(0)" ::: "memory");
    __builtin_amdgcn_sched_barrier(0);
    #pragma unroll
    for (int db = 0; db < 8; ++db) {
      short8 vf;
      vf[0] = v4[db*2][0]; vf[1] = v4[db*2][1]; vf[2] = v4[db*2][2]; vf[3] = v4[db*2][3];
      vf[4] = v4[db*2+1][0]; vf[5] = v4[db*2+1][1]; vf[6] = v4[db*2+1][2]; vf[7] = v4[db*2+1][3];
      oacc[db] = mfma16x16(pfh, vf, oacc[db]);
      oacc[db] = mfma16x16(pfl, vf, oacc[db]);
    }
    #pragma unroll
    for (int db = 0; db < 8; ++db) {
      #pragma unroll
      for (int t = 0; t < 2; ++t) {
        unsigned off = vtbl + (unsigned)((lg * 2 + t) * 1056 + db * 128);
        asm volatile("ds_read_b64_tr_b16 %0, %1" : "=v"(v4[db * 2 + t]) : "v"(off));
      }
    }
    asm volatile("s_waitcnt lgkmcnt(0)" ::: "memory");
    __builtin_amdgcn_sched_barrier(0);
    #pragma unroll
    for (int db = 0; db < 8; ++db) {
      short8 vf;
      vf[0] = v4[db*2][0]; vf[1] = v4[db*2][1]; vf[2] = v4[db*2][2]; vf[3] = v4[db*2][3];
      vf[4] = v4[db*2+1][0]; vf[5] = v4[db*2+1][1]; vf[6] = v4[db*2+1][2]; vf[7] = v4[db*2+1][3];
      oacc[db] = mfma16x16(pfh, vf, oacc[db]);
    }
    __syncthreads();
  }
  float inv[4];
  #pragma unroll
  for (int r = 0; r < 4; ++r) inv[r] = 1.0f / lreg[r];
  size_t obase = ((size_t)((b * Ss + q0 + lg * 4) * Hh + h)) * HDd + lr;
  #pragma unroll
  for (int db = 0; db < 8; ++db)
    #pragma unroll
    for (int r = 0; r < 4; ++r) {
      float val = oacc[db][r] * inv[r];
      unsigned short hb = f2bf(val);
      size_t o = obase + (size_t)r * Hh * HDd + db * 16;
      aoh[o] = hb;
      aol[o] = f2bf(val - bf2f(hb));
    }
}

// ---------- router ----------
__global__ __launch_bounds__(256) void router_logits(const float* __restrict__ x2,
                                                     const float* __restrict__ fnw,
                                                     const float* __restrict__ gw,
                                                     float* __restrict__ logits) {
  int wid = (blockIdx.x * 256 + threadIdx.x) >> 6;
  int l = threadIdx.x & 63;
  if (wid >= Tt) return;
  const float* row = x2 + (size_t)wid * Dd;
  float xs[32]; float ss = 0.f;
  #pragma unroll
  for (int c = 0; c < 32; ++c) { float t = row[c * 64 + l]; xs[c] = t; ss += t * t; }
  ss = wsum64(ss);
  float rstd = rsqrtf(ss * (1.0f / Dd) + 1e-5f);
  #pragma unroll
  for (int c = 0; c < 32; ++c) xs[c] *= rstd * fnw[c * 64 + l];
  for (int e = 0; e < 8; ++e) {
    float a = 0.f;
    #pragma unroll
    for (int c = 0; c < 32; ++c) a += xs[c] * gw[(size_t)e * Dd + c * 64 + l];
    a = wsum64(a);
    if (l == 0) logits[wid * 8 + e] = a;
  }
}
__global__ __launch_bounds__(256) void router_colstats(const float* __restrict__ logits,
                                                       float* __restrict__ mz) {
  int b = blockIdx.x >> 3, e = blockIdx.x & 7;
  int tid = threadIdx.x, wv_ = tid >> 6, l = tid & 63;
  __shared__ float red[4];
  float mx = -1e30f;
  for (int s = tid; s < Ss; s += 256) mx = fmaxf(mx, logits[(size_t)(b * Ss + s) * 8 + e]);
  #pragma unroll
  for (int d = 1; d < 64; d <<= 1) mx = fmaxf(mx, __shfl_xor(mx, d, 64));
  if (l == 0) red[wv_] = mx;
  __syncthreads();
  mx = fmaxf(fmaxf(red[0], red[1]), fmaxf(red[2], red[3]));
  __syncthreads();
  float z = 0.f;
  for (int s = tid; s < Ss; s += 256) z += expf(logits[(size_t)(b * Ss + s) * 8 + e] - mx);
  z = wsum64(z);
  if (l == 0) red[wv_] = z;
  __syncthreads();
  if (tid == 0) {
    mz[(b * 8 + e) * 2] = mx;
    mz[(b * 8 + e) * 2 + 1] = red[0] + red[1] + red[2] + red[3];
  }
}
__global__ __launch_bounds__(256) void router_select(const float* __restrict__ logits,
                                                     const float* __restrict__ mz,
                                                     int* __restrict__ sel,
                                                     float* __restrict__ ewt) {
  int t = blockIdx.x * 256 + threadIdx.x;
  if (t >= Tt) return;
  int b = t >> 10;
  float rw[8];
  #pragma unroll
  for (int e = 0; e < 8; ++e)
    rw[e] = expf(logits[(size_t)t * 8 + e] - mz[(b * 8 + e) * 2]) / mz[(b * 8 + e) * 2 + 1];
  int i0 = 0; float b0 = rw[0];
  #pragma unroll
  for (int e = 1; e < 8; ++e) if (rw[e] > b0) { b0 = rw[e]; i0 = e; }
  int i1 = -1; float b1 = -1.f;
  #pragma unroll
  for (int e = 0; e < 8; ++e) if (e != i0 && rw[e] > b1) { b1 = rw[e]; i1 = e; }
  float s = b0 + b1;
  sel[2 * t] = i0; sel[2 * t + 1] = i1;
  ewt[2 * t] = b0 / s; ewt[2 * t + 1] = b1 / s;
}
__global__ void zero_cnt_k(int* cnt) { if (threadIdx.x < 8) cnt[threadIdx.x] = 0; }
__global__ void gather_k(const int* __restrict__ sel, int* cnt, int* list) {
  int i = blockIdx.x * 256 + threadIdx.x;
  if (i >= M2) return;
  int e = sel[i];
  int pos = atomicAdd(cnt + e, 1);
  list[e * Tt + pos] = i;
}

// ---------- LoRA up via MFMA ----------
__global__ __launch_bounds__(64) void lora_up_m(const unsigned short* __restrict__ snb,
                                                const unsigned short* __restrict__ w1ab,
                                                const unsigned short* __restrict__ w3ab,
                                                const int* __restrict__ cnt,
                                                const int* __restrict__ list,
                                                float* __restrict__ t1,
                                                float* __restrict__ t3) {
  int tile = blockIdx.x, e = blockIdx.y, ks = blockIdx.z;
  int ni = cnt[e];
  if (tile * 16 >= ni) return;
  int l = threadIdx.x, lr = l & 15, lg = l >> 4;
  int slotA = tile * 16 + lr; if (slotA >= ni) slotA = ni - 1;
  int iA = list[e * Tt + slotA];
  const unsigned short* arow = snb + (size_t)(iA >> 1) * Dd + ks * 1024;
  const unsigned short* b1 = w1ab + ((size_t)e * 16 + lr) * Dd + ks * 1024;
  const unsigned short* b3 = w3ab + ((size_t)e * 16 + lr) * Dd + ks * 1024;
  f32x4 a1 = (f32x4){0.f,0.f,0.f,0.f}, a3 = (f32x4){0.f,0.f,0.f,0.f};
  #pragma unroll 4
  for (int k0 = 0; k0 < 1024; k0 += 32) {
    short8 af  = *(const short8*)(arow + k0 + lg * 8);
    short8 b1f = *(const short8*)(b1 + k0 + lg * 8);
    short8 b3f = *(const short8*)(b3 + k0 + lg * 8);
    a1 = mfma16x16(af, b1f, a1);
    a3 = mfma16x16(af, b3f, a3);
  }
  #pragma unroll
  for (int r = 0; r < 4; ++r) {
    int slot = tile * 16 + lg * 4 + r;
    if (slot < ni) {
      int i = list[e * Tt + slot];
      atomicAdd(&t1[(size_t)i * 16 + lr], a1[r]);
      atomicAdd(&t3[(size_t)i * 16 + lr], a3[r]);
    }
  }
}

// ---------- LoRA down via MFMA ----------
__global__ __launch_bounds__(64) void lora_down_m(const unsigned short* __restrict__ sr,
                                                  const unsigned short* __restrict__ w2ab,
                                                  const int* __restrict__ cnt,
                                                  const int* __restrict__ list,
                                                  float* __restrict__ t2) {
  int tile = blockIdx.x, e = blockIdx.y, ks = blockIdx.z;
  int ni = cnt[e];
  if (tile * 16 >= ni) return;
  int l = threadIdx.x, lr = l & 15, lg = l >> 4;
  int slotA = tile * 16 + lr; if (slotA >= ni) slotA = ni - 1;
  int iA = list[e * Tt + slotA];
  const unsigned short* arow = sr + (size_t)iA * Ff + ks * 1408;
  const unsigned short* brow = w2ab + ((size_t)e * 16 + lr) * Ff + ks * 1408;
  f32x4 acc = (f32x4){0.f,0.f,0.f,0.f};
  #pragma unroll 4
  for (int k0 = 0; k0 < 1408; k0 += 32) {
    short8 af = *(const short8*)(arow + k0 + lg * 8);
    short8 bf = *(const short8*)(brow + k0 + lg * 8);
    acc = mfma16x16(af, bf, acc);
  }
  #pragma unroll
  for (int r = 0; r < 4; ++r) {
    int slot = tile * 16 + lg * 4 + r;
    if (slot < ni) {
      int i = list[e * Tt + slot];
      atomicAdd(&t2[(size_t)i * 16 + lr], acc[r]);
    }
  }
}

// ---------- expert sr (reads fused c13 with stride F2) ----------
__global__ __launch_bounds__(256) void expert_sr_k(const unsigned short* __restrict__ c13,
                                                   const float* __restrict__ t1,
                                                   const float* __restrict__ t3,
                                                   const float* __restrict__ w1b,
                                                   const float* __restrict__ w3b,
                                                   const int* __restrict__ cnt,
                                                   const int* __restrict__ list,
                                                   unsigned short* __restrict__ sr) {
  int e = blockIdx.y;
  int f = blockIdx.x * 256 + threadIdx.x;
  __shared__ float W1[16 * 256], W3[16 * 256];
  #pragma unroll
  for (int r = 0; r < 16; ++r) {
    W1[r * 256 + threadIdx.x] = 2.0f * w1b[((size_t)e * Ff + f) * 16 + r];
    W3[r * 256 + threadIdx.x] = 2.0f * w3b[((size_t)e * Ff + f) * 16 + r];
  }
  __syncthreads();
  int n = cnt[e];
  int chunk = (n + 7) >> 3;
  int pbeg = blockIdx.z * chunk;
  int pend = min(n, pbeg + chunk);
  for (int p = pbeg; p < pend; ++p) {
    int i = list[e * Tt + p];
    int t = i >> 1;
    const float* u1 = t1 + (size_t)i * 16;
    const float* u3 = t3 + (size_t)i * 16;
    float l1 = 0.f, l3 = 0.f;
    #pragma unroll
    for (int r = 0; r < 16; ++r) {
      l1 += u1[r] * W1[r * 256 + threadIdx.x];
      l3 += u3[r] * W3[r * 256 + threadIdx.x];
    }
    float h1 = bf2f(c13[(size_t)t * F2 + f]) + l1;
    float h3 = bf2f(c13[(size_t)t * F2 + Ff + f]) + l3;
    float sv = (h1 / (1.f + __expf(-h1))) * h3;
    sr[(size_t)i * Ff + f] = f2bf(sv);
  }
}

// ---------- final combine (h = hb0 + hb1 split-K halves) ----------
__global__ __launch_bounds__(256) void combine_k(const float* __restrict__ hb0,
                                                 const float* __restrict__ hb1,
                                                 const float* __restrict__ t2,
                                                 const int* __restrict__ sel,
                                                 const float* __restrict__ ewt,
                                                 const float* __restrict__ w2b,
                                                 float* __restrict__ out) {
  int t = blockIdx.x;
  int d0 = threadIdx.x * 8;
  int e0 = sel[2 * t], e1 = sel[2 * t + 1];
  float a0 = ewt[2 * t], a1 = ewt[2 * t + 1];
  float uu0[16], uu1[16];
  const float* u0 = t2 + (size_t)(2 * t) * 16;
  const float* u1 = t2 + (size_t)(2 * t + 1) * 16;
  #pragma unroll
  for (int r = 0; r < 16; ++r) { uu0[r] = u0[r]; uu1[r] = u1[r]; }
  const float* wb0 = w2b + (size_t)e0 * Dd * 16;
  const float* wb1 = w2b + (size_t)e1 * Dd * 16;
  size_t r0 = (size_t)(2 * t) * Dd, r1 = (size_t)(2 * t + 1) * Dd;
  float* orow = out + (size_t)t * Dd;
  #pragma unroll
  for (int dd = 0; dd < 8; ++dd) {
    int d = d0 + dd;
    float l0 = 0.f, l1v = 0.f;
    #pragma unroll
    for (int r = 0; r < 16; ++r) {
      l0  += uu0[r] * wb0[(size_t)d * 16 + r];
      l1v += uu1[r] * wb1[(size_t)d * 16 + r];
    }
    float h0 = hb0[r0 + d] + hb1[r0 + d];
    float h1 = hb0[r1 + d] + hb1[r1 + d];
    orow[d] += a0 * (h0 + 2.f * l0) + a1 * (h1 + 2.f * l1v);
  }
}

// ---------- launch ----------
extern "C" void kernel_launch(void* const* d_in, const int* in_sizes, int n_in,
                              void* d_out, int out_size, void* d_ws, size_t ws_size,
                              hipStream_t stream) {
  const float* data  = (const float*)d_in[0];
  const float* mask  = (const float*)d_in[1];
  const float* ropec = (const float*)d_in[2];
  const float* ropes = (const float*)d_in[3];
  const float* anw   = (const float*)d_in[4];
  const float* fnw   = (const float*)d_in[5];
  const float* wq_f  = (const float*)d_in[6];
  const float* wk_f  = (const float*)d_in[7];
  const float* wv_f  = (const float*)d_in[8];
  const float* wo_f  = (const float*)d_in[9];
  const float* gate  = (const float*)d_in[10];
  const float* w1_f  = (const float*)d_in[11];
  const float* w2_f  = (const float*)d_in[12];
  const float* w3_f  = (const float*)d_in[13];
  const float* w1a   = (const float*)d_in[14];
  const float* w1bl  = (const float*)d_in[15];
  const float* w3a   = (const float*)d_in[16];
  const float* w3bl  = (const float*)d_in[17];
  const float* w2a   = (const float*)d_in[18];
  const float* w2bl  = (const float*)d_in[19];
  float* out = (float*)d_out;

  char* base = (char*)d_ws;
  size_t off = 0;
  auto take = [&](size_t bytes) -> char* {
    char* r = base + off;
    off += (bytes + 255) & ~(size_t)255;
    return r;
  };
  unsigned short* wqh = (unsigned short*)take((size_t)Dd * Dd * 2);
  unsigned short* wql = (unsigned short*)take((size_t)Dd * Dd * 2);
  unsigned short* wkh = (unsigned short*)take((size_t)NKV * Dd * 2);
  unsigned short* wkl = (unsigned short*)take((size_t)NKV * Dd * 2);
  unsigned short* wvh = (unsigned short*)take((size_t)NKV * Dd * 2);
  unsigned short* wvl = (unsigned short*)take((size_t)NKV * Dd * 2);
  unsigned short* woh = (unsigned short*)take((size_t)Dd * Dd * 2);
  unsigned short* wol = (unsigned short*)take((size_t)Dd * Dd * 2);
  unsigned short* w13bf = (unsigned short*)take((size_t)F2 * Dd * 2);  // w1 | w3 stacked
  unsigned short* w2bf  = (unsigned short*)take((size_t)Dd * Ff * 2);
  unsigned short* xh = (unsigned short*)take((size_t)Tt * Dd * 2);
  unsigned short* xl = (unsigned short*)take((size_t)Tt * Dd * 2);
  unsigned short* qhB = (unsigned short*)take((size_t)Tt * Dd * 2);
  unsigned short* qlB = (unsigned short*)take((size_t)Tt * Dd * 2);
  unsigned short* khB = (unsigned short*)take((size_t)Tt * NKV * 2);
  unsigned short* klB = (unsigned short*)take((size_t)Tt * NKV * 2);
  unsigned short* vhB = (unsigned short*)take((size_t)Tt * NKV * 2);
  unsigned short* vlB = (unsigned short*)take((size_t)Tt * NKV * 2);
  unsigned short* srb = (unsigned short*)take((size_t)M2 * Ff * 2);
  float* hb = (float*)take((size_t)M2 * Dd * 4);          // early: fused qkv f32 [Tt][4096]
  float* t1b = (float*)take((size_t)M2 * 16 * 4);
  float* t3b = (float*)take((size_t)M2 * 16 * 4);
  float* t2b = (float*)take((size_t)M2 * 16 * 4);
  int*   selb = (int*)take((size_t)M2 * 4);
  float* ewtb = (float*)take((size_t)M2 * 4);
  float* logitsb = (float*)take((size_t)Tt * 8 * 4);
  float* mzb = (float*)take((size_t)16 * 2 * 4);
  int*   cntb = (int*)take(8 * 4);
  int*   listb = (int*)take((size_t)8 * Tt * 4);
  unsigned short* w1ab = (unsigned short*)take((size_t)Ee * Rr * Dd * 2);
  unsigned short* w3ab = (unsigned short*)take((size_t)Ee * Rr * Dd * 2);
  unsigned short* w2ab = (unsigned short*)take((size_t)Ee * Rr * Ff * 2);
  if (off > ws_size) return;

  // time-disjoint aliases
  float* qkv = (float*)hb;                        // Tt x 4096 f32
  unsigned short* aoh = xh;
  unsigned short* aol = xl;
  unsigned short* snb = qhB;
  unsigned short* c13b = wqh;                     // 46.1 MB spans wqh..wol (dead weights)
  float* hb1 = (float*)xh;                        // 33.5 MB spans xh..qlB (dead by h-GEMM)

  // weight casts (fused: 2 launches)
  cast_split4<<<6144, 256, 0, stream>>>(wq_f, wk_f, wv_f, wo_f,
                                        wqh, wql, wkh, wkl, wvh, wvl, woh, wol);
  cast_all6<<<17504, 256, 0, stream>>>(w1_f, w3_f, w2_f, w1a, w3a, w2a,
                                       w13bf, w2bf, w1ab, w3ab, w2ab);
  zero_f32<<<768, 256, 0, stream>>>(t1b, 3 * M2 * 16);   // t1b,t3b,t2b contiguous

  // attention block
  rmsnorm_split_k<<<Tt, 256, 0, stream>>>(data, anw, xh, xl);
  gemm3_v4<1, 1><<<512, 512, 0, stream>>>(xh, xl, wqh, wql, wkh, wkl, wvh, wvl,
                                          Dd, Dd + NKV, qkv, nullptr, Tt, NQKV, Dd, 32);
  rope_vsplit_k<<<Tt, 512, 0, stream>>>(qkv, ropec, ropes, qhB, qlB, khB, klB, vhB, vlB);
  attn3_k<<<dim3(16, 32), 256, 0, stream>>>(qhB, qlB, khB, klB, vhB, vlB, mask, aoh, aol);
  gemm3_v4<2, 1><<<256, 512, 0, stream>>>(aoh, aol, woh, wol, woh, wol, woh, wol,
                                          Dd, Dd, d_out, data, Tt, Dd, Dd, 16);

  // FFN block
  rmsnorm_k<<<Tt, 256, 0, stream>>>(out, fnw, snb);
  router_logits<<<512, 256, 0, stream>>>(out, fnw, gate, logitsb);
  router_colstats<<<16, 256, 0, stream>>>(logitsb, mzb);
  router_select<<<8, 256, 0, stream>>>(logitsb, mzb, selb, ewtb);
  zero_cnt_k<<<1, 64, 0, stream>>>(cntb);
  gather_k<<<16, 256, 0, stream>>>(selb, cntb, listb);
  // fused c1|c3: N=11264, 1408 blocks, B-stationary (colmaj)
  gemm_bt64_v4<0, 1><<<1408, 512, 0, stream>>>(snb, w13bf, c13b, nullptr, Tt, F2, Dd, Dd, 88);
  lora_up_m<<<dim3(128, 8, 2), 64, 0, stream>>>(snb, w1ab, w3ab, cntb, listb, t1b, t3b);
  expert_sr_k<<<dim3(22, 8, 8), 256, 0, stream>>>(c13b, t1b, t3b, w1bl, w3bl, cntb, listb, srb);
  lora_down_m<<<dim3(128, 8, 4), 64, 0, stream>>>(srb, w2ab, cntb, listb, t2b);
  // h split-K=2: 1024 blocks, row-major; slice0 -> hb, slice1 -> hb1
  gemm_bt64_v4<1, 0><<<1024, 512, 0, stream>>>(srb, w2bf, hb, hb1, M2, Dd, Ff / 2, Ff, 16);
  combine_k<<<Tt, 256, 0, stream>>>(hb, hb1, t2b, selb, ewtb, w2bl, out);
}

// Round 15
// 873.300 us; speedup vs baseline: 1.0259x; 1.0064x over previous
//
#include <hip/hip_runtime.h>
#include <hip/hip_bf16.h>
#include <stdint.h>

#define DEVI __device__ __forceinline__

typedef __attribute__((ext_vector_type(8))) short short8;
typedef __attribute__((ext_vector_type(4))) short short4b;
typedef __attribute__((ext_vector_type(4))) float f32x4;

constexpr int Bb  = 2, Ss = 1024, Dd = 2048, Hh = 16, HKVv = 8, HDd = 128;
constexpr int Ff  = 5632, Ee = 8, Rr = 16;
constexpr int Tt  = Bb * Ss;        // 2048 tokens
constexpr int M2  = 2 * Tt;         // 4096 (token,slot) rows
constexpr int NKV = HKVv * HDd;     // 1024
constexpr int NQKV = Dd + 2 * NKV;  // 4096 fused qkv width
constexpr int F2  = 2 * Ff;         // 11264 fused c1|c3 width

// ---------- small helpers ----------
DEVI unsigned short f2bf(float f) {
  union { float f; unsigned u; } x; x.f = f;
  unsigned r = (x.u + 0x7FFFu + ((x.u >> 16) & 1u)) >> 16;
  return (unsigned short)r;
}
DEVI float bf2f(unsigned short h) {
  union { unsigned u; float f; } x; x.u = ((unsigned)h) << 16; return x.f;
}
DEVI float wsum64(float v) {
  #pragma unroll
  for (int d = 1; d < 64; d <<= 1) v += __shfl_xor(v, d, 64);
  return v;
}
DEVI float wsum16(float v) {
  v += __shfl_xor(v, 1, 64); v += __shfl_xor(v, 2, 64);
  v += __shfl_xor(v, 4, 64); v += __shfl_xor(v, 8, 64);
  return v;
}
DEVI float wmax16(float v) {
  v = fmaxf(v, __shfl_xor(v, 1, 64)); v = fmaxf(v, __shfl_xor(v, 2, 64));
  v = fmaxf(v, __shfl_xor(v, 4, 64)); v = fmaxf(v, __shfl_xor(v, 8, 64));
  return v;
}
typedef __attribute__((address_space(1))) void gvoid;
typedef __attribute__((address_space(3))) void lvoid;
DEVI void gl_lds16(const void* g, void* l) {
  __builtin_amdgcn_global_load_lds((gvoid*)g, (lvoid*)l, 16, 0, 0);
}
DEVI unsigned ldsoff(const void* p) {
  return (unsigned)(uintptr_t)(lvoid*)p;
}
DEVI f32x4 mfma16x16(short8 a, short8 b, f32x4 c) {
  return __builtin_amdgcn_mfma_f32_16x16x32_bf16(a, b, c, 0, 0, 0);
}
DEVI void cast8(const float* src, unsigned short* dst, size_t i) {
  const float4* p = (const float4*)(src + i);
  float4 a = p[0], b = p[1];
  float v[8] = {a.x,a.y,a.z,a.w,b.x,b.y,b.z,b.w};
  short8 o;
  #pragma unroll
  for (int j = 0; j < 8; ++j) o[j] = (short)f2bf(v[j]);
  *(short8*)(dst + i) = o;
}
DEVI void csplit8(const float* src, unsigned short* dh, unsigned short* dl, size_t i) {
  const float4* p = (const float4*)(src + i);
  float4 a = p[0], b = p[1];
  float v[8] = {a.x,a.y,a.z,a.w,b.x,b.y,b.z,b.w};
  short8 h, l;
  #pragma unroll
  for (int j = 0; j < 8; ++j) {
    unsigned short hb = f2bf(v[j]);
    h[j] = (short)hb;
    l[j] = (short)f2bf(v[j] - bf2f(hb));
  }
  *(short8*)(dh + i) = h;
  *(short8*)(dl + i) = l;
}
DEVI void rope8(const float* src, const float* cr, const float* sr,
                unsigned short* oh, unsigned short* ol) {
  const float4* px = (const float4*)src;
  float4 a = px[0], b = px[1];
  float vv[8] = {a.x,a.y,a.z,a.w,b.x,b.y,b.z,b.w};
  short8 hs, ls;
  #pragma unroll
  for (int p = 0; p < 4; ++p) {
    float x1 = vv[2 * p], x2 = vv[2 * p + 1];
    float c = cr[p], si = sr[p];
    float o1 = x1 * c - x2 * si;
    float o2 = x1 * si + x2 * c;
    unsigned short h1 = f2bf(o1), h2 = f2bf(o2);
    hs[2 * p] = (short)h1;      hs[2 * p + 1] = (short)h2;
    ls[2 * p] = (short)f2bf(o1 - bf2f(h1));
    ls[2 * p + 1] = (short)f2bf(o2 - bf2f(h2));
  }
  *(short8*)oh = hs;
  *(short8*)ol = ls;
}

// ---------- fused plain casts: 6 segments ----------
__global__ __launch_bounds__(256) void cast_all6(const float* __restrict__ w1f,
                                                 const float* __restrict__ w3f,
                                                 const float* __restrict__ w2f,
                                                 const float* __restrict__ w1a,
                                                 const float* __restrict__ w3a,
                                                 const float* __restrict__ w2a,
                                                 unsigned short* __restrict__ w13,
                                                 unsigned short* __restrict__ w2b,
                                                 unsigned short* __restrict__ w1ab,
                                                 unsigned short* __restrict__ w3ab,
                                                 unsigned short* __restrict__ w2ab) {
  int b = blockIdx.x;
  const float* src; unsigned short* dst;
  if (b < 5632)       { src = w1f; dst = w13; }
  else if (b < 11264) { src = w3f; dst = w13 + (size_t)Ff * Dd; b -= 5632; }
  else if (b < 16896) { src = w2f; dst = w2b;  b -= 11264; }
  else if (b < 17024) { src = w1a; dst = w1ab; b -= 16896; }
  else if (b < 17152) { src = w3a; dst = w3ab; b -= 17024; }
  else                { src = w2a; dst = w2ab; b -= 17152; }
  cast8(src, dst, ((size_t)b * 256 + threadIdx.x) * 8);
}

// ---------- fused split casts: 4 segments ----------
__global__ __launch_bounds__(256) void cast_split4(const float* __restrict__ wq,
                                                   const float* __restrict__ wk,
                                                   const float* __restrict__ wv,
                                                   const float* __restrict__ wo,
                                                   unsigned short* __restrict__ qh_,
                                                   unsigned short* __restrict__ ql_,
                                                   unsigned short* __restrict__ kh_,
                                                   unsigned short* __restrict__ kl_,
                                                   unsigned short* __restrict__ vh_,
                                                   unsigned short* __restrict__ vl_,
                                                   unsigned short* __restrict__ oh_,
                                                   unsigned short* __restrict__ ol_) {
  int b = blockIdx.x;
  const float* src; unsigned short* dh; unsigned short* dl;
  if (b < 2048)      { src = wq; dh = qh_; dl = ql_; }
  else if (b < 3072) { src = wk; dh = kh_; dl = kl_; b -= 2048; }
  else if (b < 4096) { src = wv; dh = vh_; dl = vl_; b -= 3072; }
  else               { src = wo; dh = oh_; dl = ol_; b -= 4096; }
  csplit8(src, dh, dl, ((size_t)b * 256 + threadIdx.x) * 8);
}

__global__ __launch_bounds__(256) void zero_f32(float* __restrict__ p, int n) {
  int i = blockIdx.x * 256 + threadIdx.x;
  if (i < n) p[i] = 0.f;
}

// ---------- rmsnorm f32 -> single bf16 ----------
__global__ __launch_bounds__(256) void rmsnorm_k(const float* __restrict__ x,
                                                 const float* __restrict__ w,
                                                 unsigned short* __restrict__ out) {
  int row = blockIdx.x, tid = threadIdx.x;
  const float* xr = x + (size_t)row * Dd;
  const float4* p4 = (const float4*)(xr + tid * 8);
  float4 a = p4[0], b = p4[1];
  float v[8] = {a.x,a.y,a.z,a.w,b.x,b.y,b.z,b.w};
  float ss = 0.f;
  #pragma unroll
  for (int j = 0; j < 8; ++j) ss += v[j] * v[j];
  ss = wsum64(ss);
  __shared__ float red[4];
  int wv_ = tid >> 6, l = tid & 63;
  if (l == 0) red[wv_] = ss;
  __syncthreads();
  float tot = red[0] + red[1] + red[2] + red[3];
  float rstd = rsqrtf(tot * (1.0f / Dd) + 1e-5f);
  const float* wr = w + tid * 8;
  short8 o;
  #pragma unroll
  for (int j = 0; j < 8; ++j) o[j] = (short)f2bf(v[j] * rstd * wr[j]);
  *(short8*)(out + (size_t)row * Dd + tid * 8) = o;
}

// ---------- rmsnorm f32 -> split bf16 pair ----------
__global__ __launch_bounds__(256) void rmsnorm_split_k(const float* __restrict__ x,
                                                       const float* __restrict__ w,
                                                       unsigned short* __restrict__ outh,
                                                       unsigned short* __restrict__ outl) {
  int row = blockIdx.x, tid = threadIdx.x;
  const float* xr = x + (size_t)row * Dd;
  const float4* p4 = (const float4*)(xr + tid * 8);
  float4 a = p4[0], b = p4[1];
  float v[8] = {a.x,a.y,a.z,a.w,b.x,b.y,b.z,b.w};
  float ss = 0.f;
  #pragma unroll
  for (int j = 0; j < 8; ++j) ss += v[j] * v[j];
  ss = wsum64(ss);
  __shared__ float red[4];
  int wv_ = tid >> 6, l = tid & 63;
  if (l == 0) red[wv_] = ss;
  __syncthreads();
  float tot = red[0] + red[1] + red[2] + red[3];
  float rstd = rsqrtf(tot * (1.0f / Dd) + 1e-5f);
  const float* wr = w + tid * 8;
  short8 oh, ol;
  #pragma unroll
  for (int j = 0; j < 8; ++j) {
    float val = v[j] * rstd * wr[j];
    unsigned short hb = f2bf(val);
    oh[j] = (short)hb;
    ol[j] = (short)f2bf(val - bf2f(hb));
  }
  *(short8*)(outh + (size_t)row * Dd + tid * 8) = oh;
  *(short8*)(outl + (size_t)row * Dd + tid * 8) = ol;
}

// ---------- bf16 GEMM v3: 8-wave/512-thread, BK=64, XOR LDS, acc 2x4, single-buffer ----------
// COLMAJ=1: by varies fastest (B-panel-stationary). ks only when COLMAJ=0.
template <int MODE, int COLMAJ>
__global__ __launch_bounds__(512) void gemm_bt64_v3(const unsigned short* __restrict__ A,
                                                    const unsigned short* __restrict__ Bw,
                                                    void* __restrict__ C0,
                                                    void* __restrict__ C1,
                                                    int M, int N, int Kext, int ld, int gx) {
  __shared__ __align__(16) unsigned short As[128 * 64];
  __shared__ __align__(16) unsigned short Bs[128 * 64];
  int tid = threadIdx.x;
  int w = tid >> 6, l = tid & 63;
  int lr = l & 15, lg = l >> 4;
  int cpx = (int)gridDim.x >> 3;
  int bid = blockIdx.x;
  int swz = (bid & 7) * cpx + (bid >> 3);
  int mtiles = M >> 7;
  int bx, by, ks = 0;
  if (COLMAJ) { by = swz % mtiles; bx = swz / mtiles; }
  else {
    bx = swz % gx; by = swz / gx;
    if (by >= mtiles) { ks = 1; by -= mtiles; }
  }
  int m0 = by * 128, n0 = bx * 128;
  int koff = ks * Kext;
  int wr = (w >> 1) * 32, wc = (w & 1) * 64;
  f32x4 acc[2][4];
  #pragma unroll
  for (int i = 0; i < 2; ++i)
    #pragma unroll
    for (int j = 0; j < 4; ++j) acc[i][j] = (f32x4){0.f, 0.f, 0.f, 0.f};

  int srow = w * 16 + (l >> 3);
  int schunk = (l & 7) ^ (l >> 3);
  const unsigned short* ga = A  + (size_t)(m0 + srow) * ld + koff + schunk * 8;
  const unsigned short* gb = Bw + (size_t)(n0 + srow) * ld + koff + schunk * 8;
  unsigned short* lA = As + w * 1024;
  unsigned short* lB = Bs + w * 1024;

  for (int k0 = 0; k0 < Kext; k0 += 64) {
    #pragma unroll
    for (int c = 0; c < 2; ++c) {
      gl_lds16(ga + k0 + (size_t)(c * 8) * ld, lA + c * 512);
      gl_lds16(gb + k0 + (size_t)(c * 8) * ld, lB + c * 512);
    }
    __syncthreads();
    #pragma unroll
    for (int kk = 0; kk < 2; ++kk) {
      int rc = ((kk * 4 + lg) ^ (lr & 7)) * 8;
      short8 af[2], bfr[4];
      #pragma unroll
      for (int i = 0; i < 2; ++i)
        af[i]  = *(const short8*)(As + (wr + i * 16 + lr) * 64 + rc);
      #pragma unroll
      for (int j = 0; j < 4; ++j)
        bfr[j] = *(const short8*)(Bs + (wc + j * 16 + lr) * 64 + rc);
      #pragma unroll
      for (int i = 0; i < 2; ++i)
        #pragma unroll
        for (int j = 0; j < 4; ++j) acc[i][j] = mfma16x16(af[i], bfr[j], acc[i][j]);
    }
    __syncthreads();
  }
  float* Cf = (float*)(ks ? C1 : C0);
  #pragma unroll
  for (int i = 0; i < 2; ++i)
    #pragma unroll
    for (int j = 0; j < 4; ++j) {
      int m = m0 + wr + i * 16 + lg * 4;
      int n = n0 + wc + j * 16 + lr;
      #pragma unroll
      for (int r = 0; r < 4; ++r) {
        float vv = acc[i][j][r];
        size_t o = (size_t)(m + r) * N + n;
        if (MODE == 0) ((unsigned short*)C0)[o] = f2bf(vv);
        else           Cf[o] = vv;
      }
    }
}

// ---------- 3-pass split-bf16 GEMM v3: 8-wave/512-thread, BK=32, swizzle v2, single-buffer ----------
template <int MODE, int COLMAJ>
__global__ __launch_bounds__(512) void gemm3_v3(const unsigned short* __restrict__ Ah,
                                                const unsigned short* __restrict__ Al,
                                                const unsigned short* __restrict__ Bh1,
                                                const unsigned short* __restrict__ Bl1,
                                                const unsigned short* __restrict__ Bh2,
                                                const unsigned short* __restrict__ Bl2,
                                                const unsigned short* __restrict__ Bh3,
                                                const unsigned short* __restrict__ Bl3,
                                                int nsplit1, int nsplit2,
                                                void* __restrict__ C0,
                                                const float* __restrict__ resid,
                                                int M, int N, int K, int gx) {
  __shared__ __align__(16) unsigned short Ash[128 * 32];
  __shared__ __align__(16) unsigned short Asl[128 * 32];
  __shared__ __align__(16) unsigned short Bsh[128 * 32];
  __shared__ __align__(16) unsigned short Bsl[128 * 32];
  int tid = threadIdx.x;
  int w = tid >> 6, l = tid & 63;
  int lr = l & 15, lg = l >> 4;
  int cpx = (int)gridDim.x >> 3;
  int bid = blockIdx.x;
  int swz = (bid & 7) * cpx + (bid >> 3);
  int mtiles = M >> 7;
  int bx, by;
  if (COLMAJ) { by = swz % mtiles; bx = swz / mtiles; }
  else        { bx = swz % gx;     by = swz / gx; }
  int m0 = by * 128, n0 = bx * 128;
  int wr = (w >> 1) * 32, wc = (w & 1) * 64;

  const unsigned short* Bh; const unsigned short* Bl; int nb;
  if (n0 < nsplit1)      { Bh = Bh1; Bl = Bl1; nb = n0; }
  else if (n0 < nsplit2) { Bh = Bh2; Bl = Bl2; nb = n0 - nsplit1; }
  else                   { Bh = Bh3; Bl = Bl3; nb = n0 - nsplit2; }

  f32x4 acc[2][4];
  #pragma unroll
  for (int i = 0; i < 2; ++i)
    #pragma unroll
    for (int j = 0; j < 4; ++j) acc[i][j] = (f32x4){0.f, 0.f, 0.f, 0.f};

  int srow = w * 16 + (l >> 2);
  int scol = ((l & 3) ^ ((l >> 3) & 3)) * 8;
  const unsigned short* gah = Ah + (size_t)(m0 + srow) * K + scol;
  const unsigned short* gal = Al + (size_t)(m0 + srow) * K + scol;
  const unsigned short* gbh = Bh + (size_t)(nb + srow) * K + scol;
  const unsigned short* gbl = Bl + (size_t)(nb + srow) * K + scol;
  unsigned short* lAh = Ash + w * 512;
  unsigned short* lAl = Asl + w * 512;
  unsigned short* lBh = Bsh + w * 512;
  unsigned short* lBl = Bsl + w * 512;

  for (int k0 = 0; k0 < K; k0 += 32) {
    gl_lds16(gah + k0, lAh);
    gl_lds16(gal + k0, lAl);
    gl_lds16(gbh + k0, lBh);
    gl_lds16(gbl + k0, lBl);
    __syncthreads();
    int rc = (lg ^ ((lr >> 1) & 3)) * 8;
    short8 afh[2], afl[2], bfh[4], bfl[4];
    #pragma unroll
    for (int i = 0; i < 2; ++i) {
      afh[i] = *(const short8*)(Ash + (wr + i * 16 + lr) * 32 + rc);
      afl[i] = *(const short8*)(Asl + (wr + i * 16 + lr) * 32 + rc);
    }
    #pragma unroll
    for (int j = 0; j < 4; ++j) {
      bfh[j] = *(const short8*)(Bsh + (wc + j * 16 + lr) * 32 + rc);
      bfl[j] = *(const short8*)(Bsl + (wc + j * 16 + lr) * 32 + rc);
    }
    #pragma unroll
    for (int i = 0; i < 2; ++i)
      #pragma unroll
      for (int j = 0; j < 4; ++j) {
        acc[i][j] = mfma16x16(afh[i], bfh[j], acc[i][j]);
        acc[i][j] = mfma16x16(afh[i], bfl[j], acc[i][j]);
        acc[i][j] = mfma16x16(afl[i], bfh[j], acc[i][j]);
      }
    __syncthreads();
  }
  #pragma unroll
  for (int i = 0; i < 2; ++i)
    #pragma unroll
    for (int j = 0; j < 4; ++j) {
      int m = m0 + wr + i * 16 + lg * 4;
      int n = n0 + wc + j * 16 + lr;
      #pragma unroll
      for (int r = 0; r < 4; ++r) {
        float vv = acc[i][j][r];
        size_t o = (size_t)(m + r) * N + n;
        if (MODE == 1) ((float*)C0)[o] = vv;
        else           ((float*)C0)[o] = vv + resid[o];
      }
    }
}

// ---------- fused rope(q) + rope(k) + vsplit ----------
__global__ __launch_bounds__(512) void rope_vsplit_k(const float* __restrict__ qkv,
                                                     const float* __restrict__ cs,
                                                     const float* __restrict__ sn,
                                                     unsigned short* __restrict__ qh_,
                                                     unsigned short* __restrict__ ql_,
                                                     unsigned short* __restrict__ kh_,
                                                     unsigned short* __restrict__ kl_,
                                                     unsigned short* __restrict__ vh_,
                                                     unsigned short* __restrict__ vl_) {
  int row = blockIdx.x;
  int s = row & (Ss - 1);
  int tid = threadIdx.x;
  const float* base = qkv + (size_t)row * NQKV;
  if (tid < 256) {
    int bas = tid * 8;
    int d = bas & (HDd - 1);
    rope8(base + bas, cs + s * 64 + (d >> 1), sn + s * 64 + (d >> 1),
          qh_ + (size_t)row * Dd + bas, ql_ + (size_t)row * Dd + bas);
  } else if (tid < 384) {
    int bas = (tid - 256) * 8;
    int d = bas & (HDd - 1);
    rope8(base + Dd + bas, cs + s * 64 + (d >> 1), sn + s * 64 + (d >> 1),
          kh_ + (size_t)row * NKV + bas, kl_ + (size_t)row * NKV + bas);
  } else {
    int bas = (tid - 384) * 8;
    const float4* p = (const float4*)(base + Dd + NKV + bas);
    float4 a = p[0], b = p[1];
    float v[8] = {a.x,a.y,a.z,a.w,b.x,b.y,b.z,b.w};
    short8 h, l;
    #pragma unroll
    for (int j = 0; j < 8; ++j) {
      unsigned short hb = f2bf(v[j]);
      h[j] = (short)hb;
      l[j] = (short)f2bf(v[j] - bf2f(hb));
    }
    size_t o = (size_t)row * NKV + bas;
    *(short8*)(vh_ + o) = h;
    *(short8*)(vl_ + o) = l;
  }
}

// ---------- flash attention, 3-pass split precision ----------
__global__ __launch_bounds__(256) void attn3_k(const unsigned short* __restrict__ qh,
                                               const unsigned short* __restrict__ ql,
                                               const unsigned short* __restrict__ kh,
                                               const unsigned short* __restrict__ kl,
                                               const unsigned short* __restrict__ vh,
                                               const unsigned short* __restrict__ vl,
                                               const float* __restrict__ mask,
                                               unsigned short* __restrict__ aoh,
                                               unsigned short* __restrict__ aol) {
  __shared__ __align__(16) unsigned short Ksh[32 * 128], Ksl[32 * 128];
  __shared__ __align__(16) unsigned short VTh[8 * 528], VTl[8 * 528];
  __shared__ __align__(16) unsigned short Plh[4 * 16 * 40], Pll[4 * 16 * 40];
  int tid = threadIdx.x, w = tid >> 6, l = tid & 63;
  int lr = l & 15, lg = l >> 4;
  int b = blockIdx.y >> 4, h = blockIdx.y & 15, hk = h >> 1;
  int q0 = blockIdx.x * 64 + w * 16;

  short8 qfh[4], qfl[4];
  {
    size_t qoff = ((size_t)(b * Ss + q0 + lr)) * Dd;
    #pragma unroll
    for (int ds = 0; ds < 4; ++ds) {
      qfh[ds] = *(const short8*)(qh + qoff + h * HDd + ds * 32 + lg * 8);
      qfl[ds] = *(const short8*)(ql + qoff + h * HDd + ds * 32 + lg * 8);
    }
  }

  float mreg[4] = {-1e30f, -1e30f, -1e30f, -1e30f};
  float lreg[4] = {0.f, 0.f, 0.f, 0.f};
  f32x4 oacc[8];
  #pragma unroll
  for (int db = 0; db < 8; ++db) oacc[db] = (f32x4){0.f, 0.f, 0.f, 0.f};

  const float sc = 0.08838834764831845f;  // 1/sqrt(128)
  size_t kvbase = ((size_t)(b * Ss)) * NKV + hk * HDd;
  const unsigned short* kb_h = kh + kvbase;
  const unsigned short* kb_l = kl + kvbase;
  const unsigned short* vb_h = vh + kvbase;
  const unsigned short* vb_l = vl + kvbase;

  int kc1 = (lr ^ lg) * 8;
  int kc2 = (lr ^ (lg + 4)) * 8;
  int vrow_a = w * 8 + ((l & 7) >> 1);
  int vchunk = ((l >> 3) * 2 + (l & 1)) * 8;
  unsigned short* vh1 = VTh + (2 * w) * 528;
  unsigned short* vh2 = VTh + (2 * w + 1) * 528;
  unsigned short* vl1 = VTl + (2 * w) * 528;
  unsigned short* vl2 = VTl + (2 * w + 1) * 528;
  unsigned vtbh = ldsoff(VTh) + (unsigned)lr * 8u;
  unsigned vtbl = ldsoff(VTl) + (unsigned)lr * 8u;

  for (int kv0 = 0; kv0 < Ss; kv0 += 32) {
    int r1 = kv0 + w * 8 + lg;
    gl_lds16(kb_h + (size_t)r1 * NKV + kc1,       Ksh + w * 1024);
    gl_lds16(kb_h + (size_t)(r1 + 4) * NKV + kc2, Ksh + w * 1024 + 512);
    gl_lds16(kb_l + (size_t)r1 * NKV + kc1,       Ksl + w * 1024);
    gl_lds16(kb_l + (size_t)(r1 + 4) * NKV + kc2, Ksl + w * 1024 + 512);
    int vr0 = kv0 + vrow_a;
    gl_lds16(vb_h + (size_t)vr0 * NKV + vchunk,       vh1);
    gl_lds16(vb_h + (size_t)(vr0 + 4) * NKV + vchunk, vh2);
    gl_lds16(vb_l + (size_t)vr0 * NKV + vchunk,       vl1);
    gl_lds16(vb_l + (size_t)(vr0 + 4) * NKV + vchunk, vl2);
    __syncthreads();

    f32x4 s0 = (f32x4){0.f,0.f,0.f,0.f}, s1 = (f32x4){0.f,0.f,0.f,0.f};
    #pragma unroll
    for (int ds = 0; ds < 4; ++ds) {
      int kcol = ((ds * 4 + lg) ^ (lr & 7)) * 8;
      short8 kh0 = *(const short8*)(Ksh + lr * 128 + kcol);
      short8 kh1 = *(const short8*)(Ksh + (16 + lr) * 128 + kcol);
      short8 kl0 = *(const short8*)(Ksl + lr * 128 + kcol);
      short8 kl1 = *(const short8*)(Ksl + (16 + lr) * 128 + kcol);
      s0 = mfma16x16(qfh[ds], kh0, s0);
      s0 = mfma16x16(qfh[ds], kl0, s0);
      s0 = mfma16x16(qfl[ds], kh0, s0);
      s1 = mfma16x16(qfh[ds], kh1, s1);
      s1 = mfma16x16(qfh[ds], kl1, s1);
      s1 = mfma16x16(qfl[ds], kh1, s1);
    }
    const float* mrow = mask + (size_t)(q0 + lg * 4) * Ss + kv0 + lr;
    #pragma unroll
    for (int r = 0; r < 4; ++r) {
      float a0 = s0[r] * sc + mrow[(size_t)r * Ss];
      float a1 = s1[r] * sc + mrow[(size_t)r * Ss + 16];
      float t = wmax16(fmaxf(a0, a1));
      float mn = fmaxf(mreg[r], t);
      float resc = __expf(mreg[r] - mn);
      mreg[r] = mn;
      float e0 = __expf(a0 - mn), e1 = __expf(a1 - mn);
      float ps = wsum16(e0 + e1);
      lreg[r] = lreg[r] * resc + ps;
      #pragma unroll
      for (int db = 0; db < 8; ++db) oacc[db][r] *= resc;
      unsigned short h0 = f2bf(e0), h1 = f2bf(e1);
      unsigned short* prowh = Plh + (w * 16 + lg * 4 + r) * 40;
      unsigned short* prowl = Pll + (w * 16 + lg * 4 + r) * 40;
      prowh[lr] = h0;            prowh[16 + lr] = h1;
      prowl[lr] = f2bf(e0 - bf2f(h0));
      prowl[16 + lr] = f2bf(e1 - bf2f(h1));
    }
    asm volatile("" ::: "memory");
    short8 pfh = *(const short8*)(Plh + (w * 16 + lr) * 40 + lg * 8);
    short8 pfl = *(const short8*)(Pll + (w * 16 + lr) * 40 + lg * 8);

    short4b v4[16];
    #pragma unroll
    for (int db = 0; db < 8; ++db) {
      #pragma unroll
      for (int t = 0; t < 2; ++t) {
        unsigned off = vtbh + (unsigned)((lg * 2 + t) * 1056 + db * 128);
        asm volatile("ds_read_b64_tr_b16 %0, %1" : "=v"(v4[db * 2 + t]) : "v"(off));
      }
    }
    asm volatile("s_waitcnt lgkmcnt(0)" ::: "memory");
    __builtin_amdgcn_sched_barrier(0);
    #pragma unroll
    for (int db = 0; db < 8; ++db) {
      short8 vf;
      vf[0] = v4[db*2][0]; vf[1] = v4[db*2][1]; vf[2] = v4[db*2][2]; vf[3] = v4[db*2][3];
      vf[4] = v4[db*2+1][0]; vf[5] = v4[db*2+1][1]; vf[6] = v4[db*2+1][2]; vf[7] = v4[db*2+1][3];
      oacc[db] = mfma16x16(pfh, vf, oacc[db]);
      oacc[db] = mfma16x16(pfl, vf, oacc[db]);
    }
    #pragma unroll
    for (int db = 0; db < 8; ++db) {
      #pragma unroll
      for (int t = 0; t < 2; ++t) {
        unsigned off = vtbl + (unsigned)((lg * 2 + t) * 1056 + db * 128);
        asm volatile("ds_read_b64_tr_b16 %0, %1" : "=v"(v4[db * 2 + t]) : "v"(off));
      }
    }
    asm volatile("s_waitcnt lgkmcnt(0)" ::: "memory");
    __builtin_amdgcn_sched_barrier(0);
    #pragma unroll
    for (int db = 0; db < 8; ++db) {
      short8 vf;
      vf[0] = v4[db*2][0]; vf[1] = v4[db*2][1]; vf[2] = v4[db*2][2]; vf[3] = v4[db*2][3];
      vf[4] = v4[db*2+1][0]; vf[5] = v4[db*2+1][1]; vf[6] = v4[db*2+1][2]; vf[7] = v4[db*2+1][3];
      oacc[db] = mfma16x16(pfh, vf, oacc[db]);
    }
    __syncthreads();
  }
  float inv[4];
  #pragma unroll
  for (int r = 0; r < 4; ++r) inv[r] = 1.0f / lreg[r];
  size_t obase = ((size_t)((b * Ss + q0 + lg * 4) * Hh + h)) * HDd + lr;
  #pragma unroll
  for (int db = 0; db < 8; ++db)
    #pragma unroll
    for (int r = 0; r < 4; ++r) {
      float val = oacc[db][r] * inv[r];
      unsigned short hb = f2bf(val);
      size_t o = obase + (size_t)r * Hh * HDd + db * 16;
      aoh[o] = hb;
      aol[o] = f2bf(val - bf2f(hb));
    }
}

// ---------- router ----------
__global__ __launch_bounds__(256) void router_logits(const float* __restrict__ x2,
                                                     const float* __restrict__ fnw,
                                                     const float* __restrict__ gw,
                                                     float* __restrict__ logits) {
  int wid = (blockIdx.x * 256 + threadIdx.x) >> 6;
  int l = threadIdx.x & 63;
  if (wid >= Tt) return;
  const float* row = x2 + (size_t)wid * Dd;
  float xs[32]; float ss = 0.f;
  #pragma unroll
  for (int c = 0; c < 32; ++c) { float t = row[c * 64 + l]; xs[c] = t; ss += t * t; }
  ss = wsum64(ss);
  float rstd = rsqrtf(ss * (1.0f / Dd) + 1e-5f);
  #pragma unroll
  for (int c = 0; c < 32; ++c) xs[c] *= rstd * fnw[c * 64 + l];
  for (int e = 0; e < 8; ++e) {
    float a = 0.f;
    #pragma unroll
    for (int c = 0; c < 32; ++c) a += xs[c] * gw[(size_t)e * Dd + c * 64 + l];
    a = wsum64(a);
    if (l == 0) logits[wid * 8 + e] = a;
  }
}
__global__ __launch_bounds__(256) void router_colstats(const float* __restrict__ logits,
                                                       float* __restrict__ mz) {
  int b = blockIdx.x >> 3, e = blockIdx.x & 7;
  int tid = threadIdx.x, wv_ = tid >> 6, l = tid & 63;
  __shared__ float red[4];
  float mx = -1e30f;
  for (int s = tid; s < Ss; s += 256) mx = fmaxf(mx, logits[(size_t)(b * Ss + s) * 8 + e]);
  #pragma unroll
  for (int d = 1; d < 64; d <<= 1) mx = fmaxf(mx, __shfl_xor(mx, d, 64));
  if (l == 0) red[wv_] = mx;
  __syncthreads();
  mx = fmaxf(fmaxf(red[0], red[1]), fmaxf(red[2], red[3]));
  __syncthreads();
  float z = 0.f;
  for (int s = tid; s < Ss; s += 256) z += expf(logits[(size_t)(b * Ss + s) * 8 + e] - mx);
  z = wsum64(z);
  if (l == 0) red[wv_] = z;
  __syncthreads();
  if (tid == 0) {
    mz[(b * 8 + e) * 2] = mx;
    mz[(b * 8 + e) * 2 + 1] = red[0] + red[1] + red[2] + red[3];
  }
}
__global__ __launch_bounds__(256) void router_select(const float* __restrict__ logits,
                                                     const float* __restrict__ mz,
                                                     int* __restrict__ sel,
                                                     float* __restrict__ ewt) {
  int t = blockIdx.x * 256 + threadIdx.x;
  if (t >= Tt) return;
  int b = t >> 10;
  float rw[8];
  #pragma unroll
  for (int e = 0; e < 8; ++e)
    rw[e] = expf(logits[(size_t)t * 8 + e] - mz[(b * 8 + e) * 2]) / mz[(b * 8 + e) * 2 + 1];
  int i0 = 0; float b0 = rw[0];
  #pragma unroll
  for (int e = 1; e < 8; ++e) if (rw[e] > b0) { b0 = rw[e]; i0 = e; }
  int i1 = -1; float b1 = -1.f;
  #pragma unroll
  for (int e = 0; e < 8; ++e) if (e != i0 && rw[e] > b1) { b1 = rw[e]; i1 = e; }
  float s = b0 + b1;
  sel[2 * t] = i0; sel[2 * t + 1] = i1;
  ewt[2 * t] = b0 / s; ewt[2 * t + 1] = b1 / s;
}
__global__ void zero_cnt_k(int* cnt) { if (threadIdx.x < 8) cnt[threadIdx.x] = 0; }
__global__ void gather_k(const int* __restrict__ sel, int* cnt, int* list) {
  int i = blockIdx.x * 256 + threadIdx.x;
  if (i >= M2) return;
  int e = sel[i];
  int pos = atomicAdd(cnt + e, 1);
  list[e * Tt + pos] = i;
}

// ---------- LoRA up via MFMA ----------
__global__ __launch_bounds__(64) void lora_up_m(const unsigned short* __restrict__ snb,
                                                const unsigned short* __restrict__ w1ab,
                                                const unsigned short* __restrict__ w3ab,
                                                const int* __restrict__ cnt,
                                                const int* __restrict__ list,
                                                float* __restrict__ t1,
                                                float* __restrict__ t3) {
  int tile = blockIdx.x, e = blockIdx.y, ks = blockIdx.z;
  int ni = cnt[e];
  if (tile * 16 >= ni) return;
  int l = threadIdx.x, lr = l & 15, lg = l >> 4;
  int slotA = tile * 16 + lr; if (slotA >= ni) slotA = ni - 1;
  int iA = list[e * Tt + slotA];
  const unsigned short* arow = snb + (size_t)(iA >> 1) * Dd + ks * 1024;
  const unsigned short* b1 = w1ab + ((size_t)e * 16 + lr) * Dd + ks * 1024;
  const unsigned short* b3 = w3ab + ((size_t)e * 16 + lr) * Dd + ks * 1024;
  f32x4 a1 = (f32x4){0.f,0.f,0.f,0.f}, a3 = (f32x4){0.f,0.f,0.f,0.f};
  #pragma unroll 4
  for (int k0 = 0; k0 < 1024; k0 += 32) {
    short8 af  = *(const short8*)(arow + k0 + lg * 8);
    short8 b1f = *(const short8*)(b1 + k0 + lg * 8);
    short8 b3f = *(const short8*)(b3 + k0 + lg * 8);
    a1 = mfma16x16(af, b1f, a1);
    a3 = mfma16x16(af, b3f, a3);
  }
  #pragma unroll
  for (int r = 0; r < 4; ++r) {
    int slot = tile * 16 + lg * 4 + r;
    if (slot < ni) {
      int i = list[e * Tt + slot];
      atomicAdd(&t1[(size_t)i * 16 + lr], a1[r]);
      atomicAdd(&t3[(size_t)i * 16 + lr], a3[r]);
    }
  }
}

// ---------- LoRA down via MFMA ----------
__global__ __launch_bounds__(64) void lora_down_m(const unsigned short* __restrict__ sr,
                                                  const unsigned short* __restrict__ w2ab,
                                                  const int* __restrict__ cnt,
                                                  const int* __restrict__ list,
                                                  float* __restrict__ t2) {
  int tile = blockIdx.x, e = blockIdx.y, ks = blockIdx.z;
  int ni = cnt[e];
  if (tile * 16 >= ni) return;
  int l = threadIdx.x, lr = l & 15, lg = l >> 4;
  int slotA = tile * 16 + lr; if (slotA >= ni) slotA = ni - 1;
  int iA = list[e * Tt + slotA];
  const unsigned short* arow = sr + (size_t)iA * Ff + ks * 1408;
  const unsigned short* brow = w2ab + ((size_t)e * 16 + lr) * Ff + ks * 1408;
  f32x4 acc = (f32x4){0.f,0.f,0.f,0.f};
  #pragma unroll 4
  for (int k0 = 0; k0 < 1408; k0 += 32) {
    short8 af = *(const short8*)(arow + k0 + lg * 8);
    short8 bf = *(const short8*)(brow + k0 + lg * 8);
    acc = mfma16x16(af, bf, acc);
  }
  #pragma unroll
  for (int r = 0; r < 4; ++r) {
    int slot = tile * 16 + lg * 4 + r;
    if (slot < ni) {
      int i = list[e * Tt + slot];
      atomicAdd(&t2[(size_t)i * 16 + lr], acc[r]);
    }
  }
}

// ---------- expert sr (reads fused c13 with stride F2) ----------
__global__ __launch_bounds__(256) void expert_sr_k(const unsigned short* __restrict__ c13,
                                                   const float* __restrict__ t1,
                                                   const float* __restrict__ t3,
                                                   const float* __restrict__ w1b,
                                                   const float* __restrict__ w3b,
                                                   const int* __restrict__ cnt,
                                                   const int* __restrict__ list,
                                                   unsigned short* __restrict__ sr) {
  int e = blockIdx.y;
  int f = blockIdx.x * 256 + threadIdx.x;
  __shared__ float W1[16 * 256], W3[16 * 256];
  #pragma unroll
  for (int r = 0; r < 16; ++r) {
    W1[r * 256 + threadIdx.x] = 2.0f * w1b[((size_t)e * Ff + f) * 16 + r];
    W3[r * 256 + threadIdx.x] = 2.0f * w3b[((size_t)e * Ff + f) * 16 + r];
  }
  __syncthreads();
  int n = cnt[e];
  int chunk = (n + 7) >> 3;
  int pbeg = blockIdx.z * chunk;
  int pend = min(n, pbeg + chunk);
  for (int p = pbeg; p < pend; ++p) {
    int i = list[e * Tt + p];
    int t = i >> 1;
    const float* u1 = t1 + (size_t)i * 16;
    const float* u3 = t3 + (size_t)i * 16;
    float l1 = 0.f, l3 = 0.f;
    #pragma unroll
    for (int r = 0; r < 16; ++r) {
      l1 += u1[r] * W1[r * 256 + threadIdx.x];
      l3 += u3[r] * W3[r * 256 + threadIdx.x];
    }
    float h1 = bf2f(c13[(size_t)t * F2 + f]) + l1;
    float h3 = bf2f(c13[(size_t)t * F2 + Ff + f]) + l3;
    float sv = (h1 / (1.f + __expf(-h1))) * h3;
    sr[(size_t)i * Ff + f] = f2bf(sv);
  }
}

// ---------- final combine (h = hb0 + hb1 split-K halves) ----------
__global__ __launch_bounds__(256) void combine_k(const float* __restrict__ hb0,
                                                 const float* __restrict__ hb1,
                                                 const float* __restrict__ t2,
                                                 const int* __restrict__ sel,
                                                 const float* __restrict__ ewt,
                                                 const float* __restrict__ w2b,
                                                 float* __restrict__ out) {
  int t = blockIdx.x;
  int d0 = threadIdx.x * 8;
  int e0 = sel[2 * t], e1 = sel[2 * t + 1];
  float a0 = ewt[2 * t], a1 = ewt[2 * t + 1];
  float uu0[16], uu1[16];
  const float* u0 = t2 + (size_t)(2 * t) * 16;
  const float* u1 = t2 + (size_t)(2 * t + 1) * 16;
  #pragma unroll
  for (int r = 0; r < 16; ++r) { uu0[r] = u0[r]; uu1[r] = u1[r]; }
  const float* wb0 = w2b + (size_t)e0 * Dd * 16;
  const float* wb1 = w2b + (size_t)e1 * Dd * 16;
  size_t r0 = (size_t)(2 * t) * Dd, r1 = (size_t)(2 * t + 1) * Dd;
  float* orow = out + (size_t)t * Dd;
  #pragma unroll
  for (int dd = 0; dd < 8; ++dd) {
    int d = d0 + dd;
    float l0 = 0.f, l1v = 0.f;
    #pragma unroll
    for (int r = 0; r < 16; ++r) {
      l0  += uu0[r] * wb0[(size_t)d * 16 + r];
      l1v += uu1[r] * wb1[(size_t)d * 16 + r];
    }
    float h0 = hb0[r0 + d] + hb1[r0 + d];
    float h1 = hb0[r1 + d] + hb1[r1 + d];
    orow[d] += a0 * (h0 + 2.f * l0) + a1 * (h1 + 2.f * l1v);
  }
}

// ---------- launch ----------
extern "C" void kernel_launch(void* const* d_in, const int* in_sizes, int n_in,
                              void* d_out, int out_size, void* d_ws, size_t ws_size,
                              hipStream_t stream) {
  const float* data  = (const float*)d_in[0];
  const float* mask  = (const float*)d_in[1];
  const float* ropec = (const float*)d_in[2];
  const float* ropes = (const float*)d_in[3];
  const float* anw   = (const float*)d_in[4];
  const float* fnw   = (const float*)d_in[5];
  const float* wq_f  = (const float*)d_in[6];
  const float* wk_f  = (const float*)d_in[7];
  const float* wv_f  = (const float*)d_in[8];
  const float* wo_f  = (const float*)d_in[9];
  const float* gate  = (const float*)d_in[10];
  const float* w1_f  = (const float*)d_in[11];
  const float* w2_f  = (const float*)d_in[12];
  const float* w3_f  = (const float*)d_in[13];
  const float* w1a   = (const float*)d_in[14];
  const float* w1bl  = (const float*)d_in[15];
  const float* w3a   = (const float*)d_in[16];
  const float* w3bl  = (const float*)d_in[17];
  const float* w2a   = (const float*)d_in[18];
  const float* w2bl  = (const float*)d_in[19];
  float* out = (float*)d_out;

  char* base = (char*)d_ws;
  size_t off = 0;
  auto take = [&](size_t bytes) -> char* {
    char* r = base + off;
    off += (bytes + 255) & ~(size_t)255;
    return r;
  };
  unsigned short* wqh = (unsigned short*)take((size_t)Dd * Dd * 2);
  unsigned short* wql = (unsigned short*)take((size_t)Dd * Dd * 2);
  unsigned short* wkh = (unsigned short*)take((size_t)NKV * Dd * 2);
  unsigned short* wkl = (unsigned short*)take((size_t)NKV * Dd * 2);
  unsigned short* wvh = (unsigned short*)take((size_t)NKV * Dd * 2);
  unsigned short* wvl = (unsigned short*)take((size_t)NKV * Dd * 2);
  unsigned short* woh = (unsigned short*)take((size_t)Dd * Dd * 2);
  unsigned short* wol = (unsigned short*)take((size_t)Dd * Dd * 2);
  unsigned short* w13bf = (unsigned short*)take((size_t)F2 * Dd * 2);
  unsigned short* w2bf  = (unsigned short*)take((size_t)Dd * Ff * 2);
  unsigned short* xh = (unsigned short*)take((size_t)Tt * Dd * 2);
  unsigned short* xl = (unsigned short*)take((size_t)Tt * Dd * 2);
  unsigned short* qhB = (unsigned short*)take((size_t)Tt * Dd * 2);
  unsigned short* qlB = (unsigned short*)take((size_t)Tt * Dd * 2);
  unsigned short* khB = (unsigned short*)take((size_t)Tt * NKV * 2);
  unsigned short* klB = (unsigned short*)take((size_t)Tt * NKV * 2);
  unsigned short* vhB = (unsigned short*)take((size_t)Tt * NKV * 2);
  unsigned short* vlB = (unsigned short*)take((size_t)Tt * NKV * 2);
  unsigned short* srb = (unsigned short*)take((size_t)M2 * Ff * 2);
  float* hb = (float*)take((size_t)M2 * Dd * 4);
  float* t1b = (float*)take((size_t)M2 * 16 * 4);
  float* t3b = (float*)take((size_t)M2 * 16 * 4);
  float* t2b = (float*)take((size_t)M2 * 16 * 4);
  int*   selb = (int*)take((size_t)M2 * 4);
  float* ewtb = (float*)take((size_t)M2 * 4);
  float* logitsb = (float*)take((size_t)Tt * 8 * 4);
  float* mzb = (float*)take((size_t)16 * 2 * 4);
  int*   cntb = (int*)take(8 * 4);
  int*   listb = (int*)take((size_t)8 * Tt * 4);
  unsigned short* w1ab = (unsigned short*)take((size_t)Ee * Rr * Dd * 2);
  unsigned short* w3ab = (unsigned short*)take((size_t)Ee * Rr * Dd * 2);
  unsigned short* w2ab = (unsigned short*)take((size_t)Ee * Rr * Ff * 2);
  if (off > ws_size) return;

  // time-disjoint aliases
  float* qkv = (float*)hb;
  unsigned short* aoh = xh;
  unsigned short* aol = xl;
  unsigned short* snb = qhB;
  unsigned short* c13b = wqh;
  float* hb1 = (float*)xh;

  // weight casts (fused: 2 launches)
  cast_split4<<<6144, 256, 0, stream>>>(wq_f, wk_f, wv_f, wo_f,
                                        wqh, wql, wkh, wkl, wvh, wvl, woh, wol);
  cast_all6<<<17504, 256, 0, stream>>>(w1_f, w3_f, w2_f, w1a, w3a, w2a,
                                       w13bf, w2bf, w1ab, w3ab, w2ab);
  zero_f32<<<768, 256, 0, stream>>>(t1b, 3 * M2 * 16);

  // attention block
  rmsnorm_split_k<<<Tt, 256, 0, stream>>>(data, anw, xh, xl);
  gemm3_v3<1, 1><<<512, 512, 0, stream>>>(xh, xl, wqh, wql, wkh, wkl, wvh, wvl,
                                          Dd, Dd + NKV, qkv, nullptr, Tt, NQKV, Dd, 32);
  rope_vsplit_k<<<Tt, 512, 0, stream>>>(qkv, ropec, ropes, qhB, qlB, khB, klB, vhB, vlB);
  attn3_k<<<dim3(16, 32), 256, 0, stream>>>(qhB, qlB, khB, klB, vhB, vlB, mask, aoh, aol);
  gemm3_v3<2, 1><<<256, 512, 0, stream>>>(aoh, aol, woh, wol, woh, wol, woh, wol,
                                          Dd, Dd, d_out, data, Tt, Dd, Dd, 16);

  // FFN block
  rmsnorm_k<<<Tt, 256, 0, stream>>>(out, fnw, snb);
  router_logits<<<512, 256, 0, stream>>>(out, fnw, gate, logitsb);
  router_colstats<<<16, 256, 0, stream>>>(logitsb, mzb);
  router_select<<<8, 256, 0, stream>>>(logitsb, mzb, selb, ewtb);
  zero_cnt_k<<<1, 64, 0, stream>>>(cntb);
  gather_k<<<16, 256, 0, stream>>>(selb, cntb, listb);
  gemm_bt64_v3<0, 1><<<1408, 512, 0, stream>>>(snb, w13bf, c13b, nullptr, Tt, F2, Dd, Dd, 88);
  lora_up_m<<<dim3(128, 8, 2), 64, 0, stream>>>(snb, w1ab, w3ab, cntb, listb, t1b, t3b);
  expert_sr_k<<<dim3(22, 8, 8), 256, 0, stream>>>(c13b, t1b, t3b, w1bl, w3bl, cntb, listb, srb);
  lora_down_m<<<dim3(128, 8, 4), 64, 0, stream>>>(srb, w2ab, cntb, listb, t2b);
  gemm_bt64_v3<1, 0><<<1024, 512, 0, stream>>>(srb, w2bf, hb, hb1, M2, Dd, Ff / 2, Ff, 16);
  combine_k<<<Tt, 256, 0, stream>>>(hb, hb1, t2b, selb, ewtb, w2bl, out);
}